// Round 10
// baseline (645.884 us; speedup 1.0000x reference)
//
#include <hip/hip_runtime.h>
#include <hip/hip_bf16.h>

// SNN forward: conv1(3->64,3x3,p1) -> IF -> pool2 -> conv2(64->64) -> IF -> pool2
//              -> fc1(16384->4096) -> IF -> fc2(4096->10) -> IF -> mean over T
// T=8 N=32 IMG=64.
// conv2 and fc1 use bf16 MFMA: spikes are exactly 0/1 (exact in bf16); fp32
// weights are 3-way bf16 split (hi+mid+lo, residual <= 2^-25|w|) -> three MFMAs
// into one fp32 accumulator == fp32 dot product to within fp32 rounding noise.
// conv1 (R10): was 48 bounds-checked stride-2 scalar loads per t per thread
// (~110 live VGPR -> regalloc serializes the batch -> exposed L2 latency each
// t). Now 12 aligned float2 loads (lane-coalesced: patch cols 2pw,2pw+1) +
// __shfl_up/__shfl_down for the halo cols (neighbor lanes own them), pw==0/31
// masked to zero = identical bounds semantics. FMA loop unchanged ->
// bit-identical output.
// fc1 (R9): W slab split3'd cooperatively ONCE per K-step into a pre-split
// bf16 LDS buffer (kills the 4x duplicated VALU that capped MFMA at 23%);
// A slab DMA double-buffered.
// conv2 (R5): A tile (zero-padded, 42.5 KB) DMA-staged per t; inner loop is
// pure ds_read_b128 + MFMA, no bounds checks; 16B-slot swizzle on DMA source.

#define T_STEPS 8
#define NB      32
#define CMID    64

typedef __bf16 bf16x2 __attribute__((ext_vector_type(2)));
typedef __bf16 bf16x4 __attribute__((ext_vector_type(4)));
typedef __bf16 bf16x8 __attribute__((ext_vector_type(8)));
typedef short  s16x4  __attribute__((ext_vector_type(4)));
typedef short  s16x8  __attribute__((ext_vector_type(8)));
typedef float  f32x4  __attribute__((ext_vector_type(4)));

struct Split3 { float h, m, l; };
__device__ __forceinline__ Split3 split3(float x) {
    Split3 s;
    __bf16 h = (__bf16)x;
    float r1 = x - (float)h;
    __bf16 m = (__bf16)r1;
    float r2 = r1 - (float)m;
    __bf16 l = (__bf16)r2;
    s.h = (float)h; s.m = (float)m; s.l = (float)l;
    return s;
}

// split 4 fp32 into three bf16x4 (hi/mid/lo), bit-identical to split3()
__device__ __forceinline__ void split3w4(float4 v, s16x4& fh, s16x4& fm,
                                         s16x4& fl) {
    float x[4] = {v.x, v.y, v.z, v.w};
    s16x4 h, m, l;
#pragma unroll
    for (int j = 0; j < 4; j++) {
        __bf16 ch = (__bf16)x[j];
        float r1 = x[j] - (float)ch;
        __bf16 cm = (__bf16)r1;
        float r2 = r1 - (float)cm;
        __bf16 cl = (__bf16)r2;
        h[j] = __builtin_bit_cast(short, ch);
        m[j] = __builtin_bit_cast(short, cm);
        l[j] = __builtin_bit_cast(short, cl);
    }
    fh = h; fm = m; fl = l;
}

// async global(16B/lane) -> LDS, wave-uniform dest base + lane*16
__device__ __forceinline__ void load_lds16(const void* g, void* l) {
    __builtin_amdgcn_global_load_lds(
        (const __attribute__((address_space(1))) void*)g,
        (__attribute__((address_space(3))) void*)l, 16, 0, 0);
}

// ------------------------------------------------- w2 -> 3-way-split frag order
// w2[co][ci][ky][kx] fp32 -> w2s[ch][tap][kh][oh][sp][lane][j] bf16 where
// co = ch*32+oh*16+(lane&15), ci = kh*32+(lane>>4)*8+j, tap = ky*3+kx.
// This is exactly the MFMA B-fragment order; conv2 blocks memcpy it into LDS.
__global__ void k_w2s(const float* __restrict__ w2, __bf16* __restrict__ w2s) {
    int idx = blockIdx.x * 256 + threadIdx.x;   // 36864 total
    int j    = idx & 7;
    int lane = (idx >> 3) & 63;
    int oh   = (idx >> 9) & 1;
    int kh   = (idx >> 10) & 1;
    int g    = idx >> 11;          // ch*9 + tap, 0..17
    int tap  = g % 9;
    int ch   = g / 9;
    int co = ch * 32 + oh * 16 + (lane & 15);
    int ci = kh * 32 + (lane >> 4) * 8 + j;
    float w = w2[co * 576 + ci * 9 + tap];
    Split3 s = split3(w);
    __bf16* o = w2s + (((size_t)(g * 2 + kh) * 2 + oh) * 3) * 512 + lane * 8 + j;
    o[0]    = (__bf16)s.h;
    o[512]  = (__bf16)s.m;
    o[1024] = (__bf16)s.l;
}

// ------------------------------------------ conv1 + IF + maxpool -> NHWC bf16
// Writes spk1p[tn][h][w][ci] bf16 (ci contiguous -> conv2 A-fragments are
// single 16B loads). Patch via aligned float2 + lane shuffles:
//   own  = x[ih][2pw..2pw+1]  (8B-aligned, lane-coalesced)
//   left = shfl_up(own.y)  -> col 2pw-1 (zero at pw==0)
//   right= shfl_down(own.x)-> col 2pw+2 (zero at pw==31)
// Same values as the old bounds-checked scalar loads -> bit-identical.
__global__ __launch_bounds__(256) void k_conv1_if_pool(
        const float* __restrict__ x, const float* __restrict__ w1,
        __bf16* __restrict__ spk1p) {
    int b   = blockIdx.x;               // 1024 = 32n * 8cog * 4pht
    int n   = b >> 5;
    int cog = (b >> 2) & 7;
    int pht = b & 3;
    int tid = threadIdx.x;
    int pw  = tid & 31;
    int ph  = pht * 8 + (tid >> 5);
    int ih0 = 2 * ph - 1;

    bool pw0  = (pw == 0);
    bool pw31 = (pw == 31);

    float v[8][4];
#pragma unroll
    for (int a = 0; a < 8; a++)
#pragma unroll
        for (int p = 0; p < 4; p++) v[a][p] = 0.f;

    for (int t = 0; t < T_STEPS; t++) {
        const float* xb = x + (size_t)(t * NB + n) * 3 * 4096;
        float patch[3][4][4];
#pragma unroll
        for (int ci = 0; ci < 3; ci++)
#pragma unroll
            for (int dy = 0; dy < 4; dy++) {
                int ih = ih0 + dy;
                float ox = 0.f, oy = 0.f;
                if ((unsigned)ih < 64u) {
                    float2 o2 = *(const float2*)(xb + ci * 4096 + ih * 64
                                                 + 2 * pw);
                    ox = o2.x; oy = o2.y;
                }
                float lft = __shfl_up(oy, 1);
                float rgt = __shfl_down(ox, 1);
                patch[ci][dy][0] = pw0 ? 0.f : lft;
                patch[ci][dy][1] = ox;
                patch[ci][dy][2] = oy;
                patch[ci][dy][3] = pw31 ? 0.f : rgt;
            }
        bf16x8 sv;
#pragma unroll
        for (int c8 = 0; c8 < 8; c8++) {
            int co = cog * 8 + c8;
            const float* wc = w1 + co * 27;   // wave-uniform -> s_load
            float a0 = 0.f, a1 = 0.f, a2 = 0.f, a3 = 0.f;
#pragma unroll
            for (int ci = 0; ci < 3; ci++)
#pragma unroll
                for (int ky = 0; ky < 3; ky++)
#pragma unroll
                    for (int kx = 0; kx < 3; kx++) {
                        float w = wc[ci * 9 + ky * 3 + kx];
                        a0 += w * patch[ci][ky][kx];
                        a1 += w * patch[ci][ky][kx + 1];
                        a2 += w * patch[ci][ky + 1][kx];
                        a3 += w * patch[ci][ky + 1][kx + 1];
                    }
            float s0, s1, s2, s3;
            v[c8][0] += a0; s0 = (v[c8][0] >= 1.f) ? 1.f : 0.f; if (s0 > 0.f) v[c8][0] = 0.f;
            v[c8][1] += a1; s1 = (v[c8][1] >= 1.f) ? 1.f : 0.f; if (s1 > 0.f) v[c8][1] = 0.f;
            v[c8][2] += a2; s2 = (v[c8][2] >= 1.f) ? 1.f : 0.f; if (s2 > 0.f) v[c8][2] = 0.f;
            v[c8][3] += a3; s3 = (v[c8][3] >= 1.f) ? 1.f : 0.f; if (s3 > 0.f) v[c8][3] = 0.f;
            sv[c8] = (__bf16)fmaxf(fmaxf(s0, s1), fmaxf(s2, s3));
        }
        *(bf16x8*)(spk1p + ((size_t)(t * NB + n) * 1024 + ph * 32 + pw) * 64
                         + cog * 8) = sv;
    }
}

// -------------------------------- conv2 (MFMA) + IF + maxpool fused, t in-kernel
// 8 waves (mh 0..3 x oh 0..1) covering 2 strips; grid 256 = 1 block/CU.
// A tile [10 rows][34 w (zero-padded)][8 slots of 16B] DMA-staged per t;
// slot swizzle: phys = logical ^ (widx&7), inverse applied on DMA source.
__global__ __launch_bounds__(512, 2) void k_conv2_if_pool(
        const short* __restrict__ spk1p,   // [256][32][32][64] bf16 bits
        const short* __restrict__ w2s,     // [2][55296] bf16 bits (frag order)
        __bf16* __restrict__ spk2) {       // [256][64][16][16]
    int b     = blockIdx.x;                // 256 = 32n * 4s2 * 2ch
    int ch    = b & 1;
    int s2    = (b >> 1) & 3;
    int n     = b >> 3;
    int tid   = threadIdx.x;
    int lane  = tid & 63;
    int wv    = tid >> 6;                  // 0..7
    int mh    = wv >> 1, oh = wv & 1;      // mh 0..3
    int lm    = lane & 15, kq = lane >> 4;

    __shared__ short Bs[55296];            // 108 KB: 9tap x 2kh x 2oh x 3sp x 512
    __shared__ short As[10 * 34 * 64];     // 42.5 KB: [r][widx][8 slots x 8 shorts]

    {
        const uint4* src = (const uint4*)(w2s + (size_t)ch * 55296);
        uint4* dst = (uint4*)Bs;
        for (int i = tid; i < 6912; i += 512) dst[i] = src[i];
        // zero whole A tile once: pad cols (widx 0,33) + out-of-image rows
        // stay zero forever (DMA never writes them).
        uint4* za = (uint4*)As;
        for (int i = tid; i < 2720; i += 512) za[i] = (uint4){0, 0, 0, 0};
    }
    __syncthreads();
    const short* Bsw = Bs + oh * 1536;

    int wl  = lane >> 3;
    int sph = lane & 7;

    f32x4 v[4];
#pragma unroll
    for (int i = 0; i < 4; i++) v[i] = (f32x4){0.f, 0.f, 0.f, 0.f};

    int co = ch * 32 + oh * 16 + lm;
    int pH = s2 * 4 + mh;

#pragma unroll 1
    for (int t = 0; t < T_STEPS; t++) {
        const short* img = spk1p + (size_t)(t * NB + n) * 65536;

        if (t > 0) __syncthreads();        // all reads of As[t-1] done
#pragma unroll
        for (int q = 0; q < 5; q++) {
            int u = q * 8 + wv;            // 0..39, wave-uniform
            int r = u >> 2;
            int quarter = u & 3;
            int hh = s2 * 8 - 1 + r;
            if ((unsigned)hh < 32u) {
                int widx = quarter * 8 + 1 + wl;
                int slog = sph ^ (widx & 7);
                const short* src = img + (size_t)(hh * 32 + widx - 1) * 64
                                       + slog * 8;
                short* dst = As + (r * 34 + quarter * 8 + 1) * 64;
                load_lds16(src, dst);
            }
        }
        __syncthreads();                   // drains DMA (vmcnt 0): As[t] ready

        f32x4 acc[4];
#pragma unroll
        for (int i = 0; i < 4; i++) acc[i] = (f32x4){0.f, 0.f, 0.f, 0.f};

#pragma unroll 1
        for (int dy = 0; dy < 3; dy++) {
#pragma unroll 1
            for (int dx = 0; dx < 3; dx++) {
                const short* bp = Bsw + (dy * 3 + dx) * 6144 + lane * 8;
                s16x8 bf[2][3];
#pragma unroll
                for (int kh = 0; kh < 2; kh++)
#pragma unroll
                    for (int sp = 0; sp < 3; sp++)
                        bf[kh][sp] = *(const s16x8*)(bp + kh * 3072 + sp * 512);
#pragma unroll
                for (int i = 0; i < 4; i++) {
                    int r    = 2 * mh + (i >> 1) + dy;              // 0..9
                    int widx = (i & 1) * 16 + lm + dx;              // 0..33
                    const short* ap = As + (r * 34 + widx) * 64;
                    s16x8 a0 = *(const s16x8*)(ap + ((kq    ) ^ (widx & 7)) * 8);
                    s16x8 a1 = *(const s16x8*)(ap + ((kq + 4) ^ (widx & 7)) * 8);
#pragma unroll
                    for (int sp = 0; sp < 3; sp++) {
                        acc[i] = __builtin_amdgcn_mfma_f32_16x16x32_bf16(
                            a0, bf[0][sp], acc[i], 0, 0, 0);
                        acc[i] = __builtin_amdgcn_mfma_f32_16x16x32_bf16(
                            a1, bf[1][sp], acc[i], 0, 0, 0);
                    }
                }
            }
        }
        // IF (charge, fire, hard reset) then 2x2 max-pool, all within-lane
        float s[4][4];
#pragma unroll
        for (int i = 0; i < 4; i++)
#pragma unroll
            for (int r = 0; r < 4; r++) {
                float vv = v[i][r] + acc[i][r];
                float sp = (vv >= 1.f) ? 1.f : 0.f;
                s[i][r] = sp;
                v[i][r] = (sp > 0.f) ? 0.f : vv;
            }
        __bf16* op = spk2 + ((size_t)(t * NB + n) * 64 + co) * 256 + pH * 16
                   + kq * 2;
#pragma unroll
        for (int i2 = 0; i2 < 2; i2++) {
            float p0 = fmaxf(fmaxf(s[i2][0], s[i2][1]),
                             fmaxf(s[i2 + 2][0], s[i2 + 2][1]));
            float p1 = fmaxf(fmaxf(s[i2][2], s[i2][3]),
                             fmaxf(s[i2 + 2][2], s[i2 + 2][3]));
            bf16x2 pv = {(__bf16)p0, (__bf16)p1};
            *(bf16x2*)(op + i2 * 8) = pv;
        }
    }
}

// ----------------------------------------------------------- fc1 via bf16 MFMA
// 512-thread blocks (8 waves: mq 0..3 x oh 0..1), grid 512 = 2 blocks/CU exact.
// Per K-step(32):
//   A slab (256 x 32k bf16, 16 KB) DMA double-buffered (swizzle
//     slot ^= ((r>>1)&3) applied on DMA source + reads).
//   W slab split ONCE cooperatively: each thread loads 1 float4 of W fp32,
//     split3 x4, writes 3x bf16x4 into Wbf[buf][sp][64][32] (16B-chunk swizzle
//     kc ^= ((row>>1)&3)). MFMA waves read ready bf16 fragments (b128, 2-way).
//   Split for it+1 runs during it's MFMAs; W(it+2) float4 prefetch in regs;
//   one __syncthreads per step.
// Same split3 bits + same MFMA order as before -> bit-identical output.
// LDS = 32 KB (A) + 24 KB (Wbf) = 56 KB -> 2 blocks/CU, 4 waves/SIMD.
__global__ __launch_bounds__(512, 4) void k_fc1_mfma(
        const short* __restrict__ A,      // spk2 bf16 bits [256][16384]
        const float* __restrict__ W,      // fc1 [4096][16384]
        float* __restrict__ part) {       // [8][256][4096]
    int b  = blockIdx.x;                  // 512 = 64nt * 8ks
    int nt = b & 63;
    int ks = b >> 6;
    int o0 = nt * 64;
    int kbase = ks * 2048;

    int tid  = threadIdx.x;
    int lane = tid & 63;
    int wv   = tid >> 6;                  // 0..7
    int mq   = wv >> 1;                   // M quarter (64 rows)
    int oh   = wv & 1;                    // output half (32 of 64)
    int lm   = lane & 15;
    int kq   = lane >> 4;

    __shared__ short Asm[2][8192];        // 2 x 16 KB A slab (swizzled)
    __shared__ short Wbf[2][6144];        // 2 x 12 KB pre-split W bf16
                                          //   [sp][row 64][chunk 4 x 8 shorts]

    // A DMA source (inverse swizzle on source; dest linear):
    // phys unit p = q*512+tid: r=p>>2, slot=(p&3)^((r>>1)&3)
    const short* gA[2];
#pragma unroll
    for (int q = 0; q < 2; q++) {
        int p = q * 512 + tid;
        int r = p >> 2;
        int c = (p & 3) ^ ((r >> 1) & 3);
        gA[q] = A + (size_t)r * 16384 + kbase + c * 8;
    }

    // W global load: thread covers row=tid>>3 (o0+row), k4=(tid&7)*4
    int wrow = tid >> 3;                  // 0..63
    const float* gWf = W + (size_t)(o0 + wrow) * 16384 + kbase + (tid & 7) * 4;

    // W bf16 write offset (shorts): row*32 + physchunk*8 + half*4 (+ sp*2048)
    int wkc   = (tid & 7) >> 1;
    int whalf = tid & 1;
    int wwoff = wrow * 32 + (wkc ^ ((wrow >> 1) & 3)) * 8 + whalf * 4;

    // LDS read offsets (swizzled)
    int aoff[4];                          // shorts
#pragma unroll
    for (int i = 0; i < 4; i++) {
        int r = mq * 64 + i * 16 + lm;
        aoff[i] = (r * 4 + (kq ^ ((r >> 1) & 3))) * 8;
    }
    int wroff[2];                         // shorts (+ sp*2048)
#pragma unroll
    for (int oi = 0; oi < 2; oi++) {
        int row = (2 * oh + oi) * 16 + lm;
        wroff[oi] = row * 32 + (kq ^ ((row >> 1) & 3)) * 8;
    }

    f32x4 acc[4][2];
#pragma unroll
    for (int i = 0; i < 4; i++)
#pragma unroll
        for (int oi = 0; oi < 2; oi++) acc[i][oi] = (f32x4){0.f, 0.f, 0.f, 0.f};

    // prologue: W(0) split -> Wbf[0]; W(1) into regs; A(0) DMA
    float4 wA = *(const float4*)gWf;          // W it=0
    load_lds16(gA[0], &Asm[0][wv * 512]);
    load_lds16(gA[1], &Asm[0][4096 + wv * 512]);
    {
        s16x4 h4, m4, l4;
        split3w4(wA, h4, m4, l4);
        *(s16x4*)&Wbf[0][wwoff]        = h4;
        *(s16x4*)&Wbf[0][2048 + wwoff] = m4;
        *(s16x4*)&Wbf[0][4096 + wwoff] = l4;
    }
    float4 wB = *(const float4*)(gWf + 32);   // W it=1
    __syncthreads();

    // body: wsplit holds W(it+1) fp32; wload will receive W(it+2)
    auto body = [&](int it, float4& wsplit, float4& wload) {
        int nb = (it + 1) & 1;
        if (it < 63) {
            load_lds16(gA[0] + (it + 1) * 32, &Asm[nb][wv * 512]);
            load_lds16(gA[1] + (it + 1) * 32, &Asm[nb][4096 + wv * 512]);
            s16x4 h4, m4, l4;
            split3w4(wsplit, h4, m4, l4);
            *(s16x4*)&Wbf[nb][wwoff]        = h4;
            *(s16x4*)&Wbf[nb][2048 + wwoff] = m4;
            *(s16x4*)&Wbf[nb][4096 + wwoff] = l4;
        }
        if (it < 62)
            wload = *(const float4*)(gWf + (it + 2) * 32);

        const short* as = Asm[it & 1];
        const short* wb = Wbf[it & 1];
        s16x8 av[4];
#pragma unroll
        for (int i = 0; i < 4; i++)
            av[i] = *(const s16x8*)(as + aoff[i]);
        s16x8 bfr[3][2];                  // [sp][oi]
#pragma unroll
        for (int oi = 0; oi < 2; oi++)
#pragma unroll
            for (int sp = 0; sp < 3; sp++)
                bfr[sp][oi] = *(const s16x8*)(wb + sp * 2048 + wroff[oi]);

#pragma unroll
        for (int i = 0; i < 4; i++)
#pragma unroll
            for (int oi = 0; oi < 2; oi++) {
                acc[i][oi] = __builtin_amdgcn_mfma_f32_16x16x32_bf16(
                    av[i], bfr[0][oi], acc[i][oi], 0, 0, 0);
                acc[i][oi] = __builtin_amdgcn_mfma_f32_16x16x32_bf16(
                    av[i], bfr[1][oi], acc[i][oi], 0, 0, 0);
                acc[i][oi] = __builtin_amdgcn_mfma_f32_16x16x32_bf16(
                    av[i], bfr[2][oi], acc[i][oi], 0, 0, 0);
            }

        __syncthreads();                  // drains DMA + ds_writes; swap
    };

#pragma unroll 1
    for (int j = 0; j < 32; ++j) {
        body(2 * j,     wB, wA);
        body(2 * j + 1, wA, wB);
    }

    int col = lane & 15;
    int rq  = (lane >> 4) * 4;
#pragma unroll
    for (int i = 0; i < 4; i++)
#pragma unroll
        for (int oi = 0; oi < 2; oi++)
#pragma unroll
            for (int r = 0; r < 4; r++) {
                int m = mq * 64 + i * 16 + rq + r;
                int o = o0 + (2 * oh + oi) * 16 + col;
                part[((size_t)ks * 256 + m) * 4096 + o] = acc[i][oi][r];
            }
}

// ----------------------------------------------- K-split reduce + IF for fc1
__global__ void k_fc1_if(const float* __restrict__ part,
                         float* __restrict__ spk3) {
    int idx = blockIdx.x * 256 + threadIdx.x;   // 131072
    int o = idx & 4095;
    int n = idx >> 12;
    float v = 0.f;
    for (int t = 0; t < T_STEPS; t++) {
        int m = t * NB + n;
        float s = 0.f;
#pragma unroll
        for (int ks = 0; ks < 8; ks++)
            s += part[((size_t)ks * 256 + m) * 4096 + o];
        v += s;
        float sp = (v >= 1.f) ? 1.f : 0.f;
        if (sp > 0.f) v = 0.f;
        spk3[(size_t)m * 4096 + o] = sp;
    }
}

// ------------------------------------------------------ fc2 + IF + time-mean
__global__ __launch_bounds__(256) void k_fc2_if_mean(
        const float* __restrict__ spk3, const float* __restrict__ fc2,
        float* __restrict__ out) {
    int b = blockIdx.x;                  // 320 = 32n * 10o
    int n = b / 10, o = b % 10;
    const float* wr = fc2 + o * 4096;
    __shared__ float red[256];
    int tid = threadIdx.x;
    float v = 0.f, cnt = 0.f;
    for (int t = 0; t < T_STEPS; t++) {
        const float* row = spk3 + (size_t)(t * NB + n) * 4096;
        float p = 0.f;
        for (int i = tid; i < 4096; i += 256) p += row[i] * wr[i];
        red[tid] = p;
        __syncthreads();
        for (int s = 128; s > 0; s >>= 1) {
            if (tid < s) red[tid] += red[tid + s];
            __syncthreads();
        }
        if (tid == 0) {
            v += red[0];
            float sp = (v >= 1.f) ? 1.f : 0.f;
            cnt += sp;
            if (sp > 0.f) v = 0.f;
        }
        __syncthreads();
    }
    if (tid == 0) out[n * 10 + o] = cnt * 0.125f;
}

// ---------------------------------------------------------------------- launch
extern "C" void kernel_launch(void* const* d_in, const int* in_sizes, int n_in,
                              void* d_out, int out_size, void* d_ws, size_t ws_size,
                              hipStream_t stream) {
    const float* x   = (const float*)d_in[0];   // [8,32,3,64,64]
    const float* w1  = (const float*)d_in[1];   // [64,3,3,3]
    const float* w2  = (const float*)d_in[2];   // [64,64,3,3]
    const float* fc1 = (const float*)d_in[3];   // [4096,16384]
    const float* fc2 = (const float*)d_in[4];   // [10,4096]
    float* out = (float*)d_out;                 // [32,10]

    float* ws = (float*)d_ws;
    // workspace layout (float slots)
    const size_t off_w2s   = 0;                          // 57344 (110592 bf16)
    const size_t off_spk1p = 57344;                      // 8388608 (16.8M bf16)
    const size_t off_spk2  = off_spk1p + 8388608;        // 2097152 (4.2M bf16)
    const size_t off_part  = off_spk2 + 2097152;         // 8388608
    const size_t off_spk3  = off_part + 8388608;         // 1048576
    __bf16* w2s   = (__bf16*)(ws + off_w2s);
    __bf16* spk1p = (__bf16*)(ws + off_spk1p);
    __bf16* spk2  = (__bf16*)(ws + off_spk2);
    float*  part  = ws + off_part;
    float*  spk3  = ws + off_spk3;

    k_w2s<<<144, 256, 0, stream>>>(w2, w2s);
    k_conv1_if_pool<<<1024, 256, 0, stream>>>(x, w1, spk1p);
    k_conv2_if_pool<<<256, 512, 0, stream>>>((const short*)spk1p,
                                             (const short*)w2s, spk2);
    k_fc1_mfma<<<512, 512, 0, stream>>>((const short*)spk2, fc1, part);
    k_fc1_if<<<512, 256, 0, stream>>>(part, spk3);
    k_fc2_if_mean<<<320, 256, 0, stream>>>(spk3, fc2, out);
}

// Round 11
// 626.766 us; speedup vs baseline: 1.0305x; 1.0305x over previous
//
#include <hip/hip_runtime.h>
#include <hip/hip_bf16.h>

// SNN forward: conv1(3->64,3x3,p1) -> IF -> pool2 -> conv2(64->64) -> IF -> pool2
//              -> fc1(16384->4096) -> IF -> fc2(4096->10) -> IF -> mean over T
// T=8 N=32 IMG=64.
// conv2 and fc1 use bf16 MFMA: spikes are exactly 0/1 (exact in bf16); fp32
// weights are 3-way bf16 split (hi+mid+lo, residual <= 2^-25|w|) -> three MFMAs
// into one fp32 accumulator == fp32 dot product to within fp32 rounding noise.
// conv1: R9 scalar-patch version (R10's shuffle rewrite regressed ~17us —
// fewer loads lost to added VALU + dependency chains; loads were L2/L3-served).
// fc1 (R11): R9 structure (cooperative W split3 -> pre-split bf16 LDS; A slab
// DMA double-buffered) + counted-vmcnt barrier: end-of-body
// s_waitcnt vmcnt(1) lgkmcnt(0); s_barrier — the W(it+2) register prefetch
// stays in flight across the barrier (old __syncthreads drained vmcnt(0),
// exposing W HBM/L3 latency every body now that R9 removed the VALU wall).
// conv2 (R5): A tile (zero-padded, 42.5 KB) DMA-staged per t; inner loop is
// pure ds_read_b128 + MFMA, no bounds checks; 16B-slot swizzle on DMA source.

#define T_STEPS 8
#define NB      32
#define CMID    64

typedef __bf16 bf16x2 __attribute__((ext_vector_type(2)));
typedef __bf16 bf16x4 __attribute__((ext_vector_type(4)));
typedef __bf16 bf16x8 __attribute__((ext_vector_type(8)));
typedef short  s16x4  __attribute__((ext_vector_type(4)));
typedef short  s16x8  __attribute__((ext_vector_type(8)));
typedef float  f32x4  __attribute__((ext_vector_type(4)));

struct Split3 { float h, m, l; };
__device__ __forceinline__ Split3 split3(float x) {
    Split3 s;
    __bf16 h = (__bf16)x;
    float r1 = x - (float)h;
    __bf16 m = (__bf16)r1;
    float r2 = r1 - (float)m;
    __bf16 l = (__bf16)r2;
    s.h = (float)h; s.m = (float)m; s.l = (float)l;
    return s;
}

// split 4 fp32 into three bf16x4 (hi/mid/lo), bit-identical to split3()
__device__ __forceinline__ void split3w4(float4 v, s16x4& fh, s16x4& fm,
                                         s16x4& fl) {
    float x[4] = {v.x, v.y, v.z, v.w};
    s16x4 h, m, l;
#pragma unroll
    for (int j = 0; j < 4; j++) {
        __bf16 ch = (__bf16)x[j];
        float r1 = x[j] - (float)ch;
        __bf16 cm = (__bf16)r1;
        float r2 = r1 - (float)cm;
        __bf16 cl = (__bf16)r2;
        h[j] = __builtin_bit_cast(short, ch);
        m[j] = __builtin_bit_cast(short, cm);
        l[j] = __builtin_bit_cast(short, cl);
    }
    fh = h; fm = m; fl = l;
}

// async global(16B/lane) -> LDS, wave-uniform dest base + lane*16
__device__ __forceinline__ void load_lds16(const void* g, void* l) {
    __builtin_amdgcn_global_load_lds(
        (const __attribute__((address_space(1))) void*)g,
        (__attribute__((address_space(3))) void*)l, 16, 0, 0);
}

// ------------------------------------------------- w2 -> 3-way-split frag order
// w2[co][ci][ky][kx] fp32 -> w2s[ch][tap][kh][oh][sp][lane][j] bf16 where
// co = ch*32+oh*16+(lane&15), ci = kh*32+(lane>>4)*8+j, tap = ky*3+kx.
// This is exactly the MFMA B-fragment order; conv2 blocks memcpy it into LDS.
__global__ void k_w2s(const float* __restrict__ w2, __bf16* __restrict__ w2s) {
    int idx = blockIdx.x * 256 + threadIdx.x;   // 36864 total
    int j    = idx & 7;
    int lane = (idx >> 3) & 63;
    int oh   = (idx >> 9) & 1;
    int kh   = (idx >> 10) & 1;
    int g    = idx >> 11;          // ch*9 + tap, 0..17
    int tap  = g % 9;
    int ch   = g / 9;
    int co = ch * 32 + oh * 16 + (lane & 15);
    int ci = kh * 32 + (lane >> 4) * 8 + j;
    float w = w2[co * 576 + ci * 9 + tap];
    Split3 s = split3(w);
    __bf16* o = w2s + (((size_t)(g * 2 + kh) * 2 + oh) * 3) * 512 + lane * 8 + j;
    o[0]    = (__bf16)s.h;
    o[512]  = (__bf16)s.m;
    o[1024] = (__bf16)s.l;
}

// ------------------------------------------ conv1 + IF + maxpool -> NHWC bf16
// Writes spk1p[tn][h][w][ci] bf16 (ci contiguous -> conv2 A-fragments are
// single 16B loads).
__global__ __launch_bounds__(256) void k_conv1_if_pool(
        const float* __restrict__ x, const float* __restrict__ w1,
        __bf16* __restrict__ spk1p) {
    int b   = blockIdx.x;               // 1024 = 32n * 8cog * 4pht
    int n   = b >> 5;
    int cog = (b >> 2) & 7;
    int pht = b & 3;
    int tid = threadIdx.x;
    int pw  = tid & 31;
    int ph  = pht * 8 + (tid >> 5);
    int ih0 = 2 * ph - 1, iw0 = 2 * pw - 1;

    float v[8][4];
#pragma unroll
    for (int a = 0; a < 8; a++)
#pragma unroll
        for (int p = 0; p < 4; p++) v[a][p] = 0.f;

    for (int t = 0; t < T_STEPS; t++) {
        const float* xb = x + (size_t)(t * NB + n) * 3 * 4096;
        float patch[3][4][4];
#pragma unroll
        for (int ci = 0; ci < 3; ci++)
#pragma unroll
            for (int dy = 0; dy < 4; dy++) {
                int ih = ih0 + dy;
                bool rok = ((unsigned)ih < 64u);
#pragma unroll
                for (int dx = 0; dx < 4; dx++) {
                    int iw = iw0 + dx;
                    patch[ci][dy][dx] = (rok && ((unsigned)iw < 64u))
                                            ? xb[ci * 4096 + ih * 64 + iw] : 0.f;
                }
            }
        bf16x8 sv;
#pragma unroll
        for (int c8 = 0; c8 < 8; c8++) {
            int co = cog * 8 + c8;
            const float* wc = w1 + co * 27;   // wave-uniform -> s_load
            float a0 = 0.f, a1 = 0.f, a2 = 0.f, a3 = 0.f;
#pragma unroll
            for (int ci = 0; ci < 3; ci++)
#pragma unroll
                for (int ky = 0; ky < 3; ky++)
#pragma unroll
                    for (int kx = 0; kx < 3; kx++) {
                        float w = wc[ci * 9 + ky * 3 + kx];
                        a0 += w * patch[ci][ky][kx];
                        a1 += w * patch[ci][ky][kx + 1];
                        a2 += w * patch[ci][ky + 1][kx];
                        a3 += w * patch[ci][ky + 1][kx + 1];
                    }
            float s0, s1, s2, s3;
            v[c8][0] += a0; s0 = (v[c8][0] >= 1.f) ? 1.f : 0.f; if (s0 > 0.f) v[c8][0] = 0.f;
            v[c8][1] += a1; s1 = (v[c8][1] >= 1.f) ? 1.f : 0.f; if (s1 > 0.f) v[c8][1] = 0.f;
            v[c8][2] += a2; s2 = (v[c8][2] >= 1.f) ? 1.f : 0.f; if (s2 > 0.f) v[c8][2] = 0.f;
            v[c8][3] += a3; s3 = (v[c8][3] >= 1.f) ? 1.f : 0.f; if (s3 > 0.f) v[c8][3] = 0.f;
            sv[c8] = (__bf16)fmaxf(fmaxf(s0, s1), fmaxf(s2, s3));
        }
        *(bf16x8*)(spk1p + ((size_t)(t * NB + n) * 1024 + ph * 32 + pw) * 64
                         + cog * 8) = sv;
    }
}

// -------------------------------- conv2 (MFMA) + IF + maxpool fused, t in-kernel
// 8 waves (mh 0..3 x oh 0..1) covering 2 strips; grid 256 = 1 block/CU.
// A tile [10 rows][34 w (zero-padded)][8 slots of 16B] DMA-staged per t;
// slot swizzle: phys = logical ^ (widx&7), inverse applied on DMA source.
__global__ __launch_bounds__(512, 2) void k_conv2_if_pool(
        const short* __restrict__ spk1p,   // [256][32][32][64] bf16 bits
        const short* __restrict__ w2s,     // [2][55296] bf16 bits (frag order)
        __bf16* __restrict__ spk2) {       // [256][64][16][16]
    int b     = blockIdx.x;                // 256 = 32n * 4s2 * 2ch
    int ch    = b & 1;
    int s2    = (b >> 1) & 3;
    int n     = b >> 3;
    int tid   = threadIdx.x;
    int lane  = tid & 63;
    int wv    = tid >> 6;                  // 0..7
    int mh    = wv >> 1, oh = wv & 1;      // mh 0..3
    int lm    = lane & 15, kq = lane >> 4;

    __shared__ short Bs[55296];            // 108 KB: 9tap x 2kh x 2oh x 3sp x 512
    __shared__ short As[10 * 34 * 64];     // 42.5 KB: [r][widx][8 slots x 8 shorts]

    {
        const uint4* src = (const uint4*)(w2s + (size_t)ch * 55296);
        uint4* dst = (uint4*)Bs;
        for (int i = tid; i < 6912; i += 512) dst[i] = src[i];
        // zero whole A tile once: pad cols (widx 0,33) + out-of-image rows
        // stay zero forever (DMA never writes them).
        uint4* za = (uint4*)As;
        for (int i = tid; i < 2720; i += 512) za[i] = (uint4){0, 0, 0, 0};
    }
    __syncthreads();
    const short* Bsw = Bs + oh * 1536;

    int wl  = lane >> 3;
    int sph = lane & 7;

    f32x4 v[4];
#pragma unroll
    for (int i = 0; i < 4; i++) v[i] = (f32x4){0.f, 0.f, 0.f, 0.f};

    int co = ch * 32 + oh * 16 + lm;
    int pH = s2 * 4 + mh;

#pragma unroll 1
    for (int t = 0; t < T_STEPS; t++) {
        const short* img = spk1p + (size_t)(t * NB + n) * 65536;

        if (t > 0) __syncthreads();        // all reads of As[t-1] done
#pragma unroll
        for (int q = 0; q < 5; q++) {
            int u = q * 8 + wv;            // 0..39, wave-uniform
            int r = u >> 2;
            int quarter = u & 3;
            int hh = s2 * 8 - 1 + r;
            if ((unsigned)hh < 32u) {
                int widx = quarter * 8 + 1 + wl;
                int slog = sph ^ (widx & 7);
                const short* src = img + (size_t)(hh * 32 + widx - 1) * 64
                                       + slog * 8;
                short* dst = As + (r * 34 + quarter * 8 + 1) * 64;
                load_lds16(src, dst);
            }
        }
        __syncthreads();                   // drains DMA (vmcnt 0): As[t] ready

        f32x4 acc[4];
#pragma unroll
        for (int i = 0; i < 4; i++) acc[i] = (f32x4){0.f, 0.f, 0.f, 0.f};

#pragma unroll 1
        for (int dy = 0; dy < 3; dy++) {
#pragma unroll 1
            for (int dx = 0; dx < 3; dx++) {
                const short* bp = Bsw + (dy * 3 + dx) * 6144 + lane * 8;
                s16x8 bf[2][3];
#pragma unroll
                for (int kh = 0; kh < 2; kh++)
#pragma unroll
                    for (int sp = 0; sp < 3; sp++)
                        bf[kh][sp] = *(const s16x8*)(bp + kh * 3072 + sp * 512);
#pragma unroll
                for (int i = 0; i < 4; i++) {
                    int r    = 2 * mh + (i >> 1) + dy;              // 0..9
                    int widx = (i & 1) * 16 + lm + dx;              // 0..33
                    const short* ap = As + (r * 34 + widx) * 64;
                    s16x8 a0 = *(const s16x8*)(ap + ((kq    ) ^ (widx & 7)) * 8);
                    s16x8 a1 = *(const s16x8*)(ap + ((kq + 4) ^ (widx & 7)) * 8);
#pragma unroll
                    for (int sp = 0; sp < 3; sp++) {
                        acc[i] = __builtin_amdgcn_mfma_f32_16x16x32_bf16(
                            a0, bf[0][sp], acc[i], 0, 0, 0);
                        acc[i] = __builtin_amdgcn_mfma_f32_16x16x32_bf16(
                            a1, bf[1][sp], acc[i], 0, 0, 0);
                    }
                }
            }
        }
        // IF (charge, fire, hard reset) then 2x2 max-pool, all within-lane
        float s[4][4];
#pragma unroll
        for (int i = 0; i < 4; i++)
#pragma unroll
            for (int r = 0; r < 4; r++) {
                float vv = v[i][r] + acc[i][r];
                float sp = (vv >= 1.f) ? 1.f : 0.f;
                s[i][r] = sp;
                v[i][r] = (sp > 0.f) ? 0.f : vv;
            }
        __bf16* op = spk2 + ((size_t)(t * NB + n) * 64 + co) * 256 + pH * 16
                   + kq * 2;
#pragma unroll
        for (int i2 = 0; i2 < 2; i2++) {
            float p0 = fmaxf(fmaxf(s[i2][0], s[i2][1]),
                             fmaxf(s[i2 + 2][0], s[i2 + 2][1]));
            float p1 = fmaxf(fmaxf(s[i2][2], s[i2][3]),
                             fmaxf(s[i2 + 2][2], s[i2 + 2][3]));
            bf16x2 pv = {(__bf16)p0, (__bf16)p1};
            *(bf16x2*)(op + i2 * 8) = pv;
        }
    }
}

// ----------------------------------------------------------- fc1 via bf16 MFMA
// 512-thread blocks (8 waves: mq 0..3 x oh 0..1), grid 512 = 2 blocks/CU exact.
// Per K-step(32):
//   A slab (256 x 32k bf16, 16 KB) DMA double-buffered (swizzle
//     slot ^= ((r>>1)&3) applied on DMA source + reads).
//   W slab split ONCE cooperatively: each thread loads 1 float4 of W fp32,
//     split3 x4, writes 3x bf16x4 into Wbf[buf][sp][64][32] (16B-chunk swizzle
//     kc ^= ((row>>1)&3)). MFMA waves read ready bf16 fragments (b128, 2-way).
//   Split for it+1 runs during it's MFMAs; W(it+2) float4 prefetch in regs.
// R11: counted-vmcnt barrier. VMEM issue order pinned (sched_barrier): A-DMA
// x2 then wload. End-of-body: s_waitcnt vmcnt(1) lgkmcnt(0); s_barrier ->
// A(it+1) DMAs complete + Wbf writes visible, W(it+2) reg-load stays in
// flight across the barrier (old __syncthreads drained it to vmcnt 0).
// Same split3 bits + same MFMA order as before -> bit-identical output.
// LDS = 32 KB (A) + 24 KB (Wbf) = 56 KB -> 2 blocks/CU, 4 waves/SIMD.
__global__ __launch_bounds__(512, 4) void k_fc1_mfma(
        const short* __restrict__ A,      // spk2 bf16 bits [256][16384]
        const float* __restrict__ W,      // fc1 [4096][16384]
        float* __restrict__ part) {       // [8][256][4096]
    int b  = blockIdx.x;                  // 512 = 64nt * 8ks
    int nt = b & 63;
    int ks = b >> 6;
    int o0 = nt * 64;
    int kbase = ks * 2048;

    int tid  = threadIdx.x;
    int lane = tid & 63;
    int wv   = tid >> 6;                  // 0..7
    int mq   = wv >> 1;                   // M quarter (64 rows)
    int oh   = wv & 1;                    // output half (32 of 64)
    int lm   = lane & 15;
    int kq   = lane >> 4;

    __shared__ short Asm[2][8192];        // 2 x 16 KB A slab (swizzled)
    __shared__ short Wbf[2][6144];        // 2 x 12 KB pre-split W bf16
                                          //   [sp][row 64][chunk 4 x 8 shorts]

    // A DMA source (inverse swizzle on source; dest linear):
    // phys unit p = q*512+tid: r=p>>2, slot=(p&3)^((r>>1)&3)
    const short* gA[2];
#pragma unroll
    for (int q = 0; q < 2; q++) {
        int p = q * 512 + tid;
        int r = p >> 2;
        int c = (p & 3) ^ ((r >> 1) & 3);
        gA[q] = A + (size_t)r * 16384 + kbase + c * 8;
    }

    // W global load: thread covers row=tid>>3 (o0+row), k4=(tid&7)*4
    int wrow = tid >> 3;                  // 0..63
    const float* gWf = W + (size_t)(o0 + wrow) * 16384 + kbase + (tid & 7) * 4;

    // W bf16 write offset (shorts): row*32 + physchunk*8 + half*4 (+ sp*2048)
    int wkc   = (tid & 7) >> 1;
    int whalf = tid & 1;
    int wwoff = wrow * 32 + (wkc ^ ((wrow >> 1) & 3)) * 8 + whalf * 4;

    // LDS read offsets (swizzled)
    int aoff[4];                          // shorts
#pragma unroll
    for (int i = 0; i < 4; i++) {
        int r = mq * 64 + i * 16 + lm;
        aoff[i] = (r * 4 + (kq ^ ((r >> 1) & 3))) * 8;
    }
    int wroff[2];                         // shorts (+ sp*2048)
#pragma unroll
    for (int oi = 0; oi < 2; oi++) {
        int row = (2 * oh + oi) * 16 + lm;
        wroff[oi] = row * 32 + (kq ^ ((row >> 1) & 3)) * 8;
    }

    f32x4 acc[4][2];
#pragma unroll
    for (int i = 0; i < 4; i++)
#pragma unroll
        for (int oi = 0; oi < 2; oi++) acc[i][oi] = (f32x4){0.f, 0.f, 0.f, 0.f};

    // prologue: W(0) split -> Wbf[0]; W(1) into regs; A(0) DMA
    float4 wA = *(const float4*)gWf;          // W it=0
    load_lds16(gA[0], &Asm[0][wv * 512]);
    load_lds16(gA[1], &Asm[0][4096 + wv * 512]);
    {
        s16x4 h4, m4, l4;
        split3w4(wA, h4, m4, l4);
        *(s16x4*)&Wbf[0][wwoff]        = h4;
        *(s16x4*)&Wbf[0][2048 + wwoff] = m4;
        *(s16x4*)&Wbf[0][4096 + wwoff] = l4;
    }
    float4 wB = *(const float4*)(gWf + 32);   // W it=1
    __syncthreads();

    // body: wsplit holds W(it+1) fp32; wload will receive W(it+2)
    auto body = [&](int it, float4& wsplit, float4& wload) {
        int nb = (it + 1) & 1;
        if (it < 63) {
            // A-DMA for it+1 issued FIRST (oldest in vm queue)
            load_lds16(gA[0] + (it + 1) * 32, &Asm[nb][wv * 512]);
            load_lds16(gA[1] + (it + 1) * 32, &Asm[nb][4096 + wv * 512]);
            __builtin_amdgcn_sched_barrier(0);   // pin: DMAs before wload
            s16x4 h4, m4, l4;
            split3w4(wsplit, h4, m4, l4);
            *(s16x4*)&Wbf[nb][wwoff]        = h4;
            *(s16x4*)&Wbf[nb][2048 + wwoff] = m4;
            *(s16x4*)&Wbf[nb][4096 + wwoff] = l4;
        }
        if (it < 62) {
            wload = *(const float4*)(gWf + (it + 2) * 32);
            __builtin_amdgcn_sched_barrier(0);   // pin: wload issued here
        }

        const short* as = Asm[it & 1];
        const short* wb = Wbf[it & 1];
        s16x8 av[4];
#pragma unroll
        for (int i = 0; i < 4; i++)
            av[i] = *(const s16x8*)(as + aoff[i]);
        s16x8 bfr[3][2];                  // [sp][oi]
#pragma unroll
        for (int oi = 0; oi < 2; oi++)
#pragma unroll
            for (int sp = 0; sp < 3; sp++)
                bfr[sp][oi] = *(const s16x8*)(wb + sp * 2048 + wroff[oi]);

#pragma unroll
        for (int i = 0; i < 4; i++)
#pragma unroll
            for (int oi = 0; oi < 2; oi++) {
                acc[i][oi] = __builtin_amdgcn_mfma_f32_16x16x32_bf16(
                    av[i], bfr[0][oi], acc[i][oi], 0, 0, 0);
                acc[i][oi] = __builtin_amdgcn_mfma_f32_16x16x32_bf16(
                    av[i], bfr[1][oi], acc[i][oi], 0, 0, 0);
                acc[i][oi] = __builtin_amdgcn_mfma_f32_16x16x32_bf16(
                    av[i], bfr[2][oi], acc[i][oi], 0, 0, 0);
            }

        // counted sync: A(it+1) DMAs done + ds_writes visible; W(it+2)
        // register load stays in flight across the barrier.
        if (it < 62) {
            asm volatile("s_waitcnt vmcnt(1) lgkmcnt(0)" ::: "memory");
            __builtin_amdgcn_s_barrier();
            __builtin_amdgcn_sched_barrier(0);
        } else if (it == 62) {
            asm volatile("s_waitcnt vmcnt(0) lgkmcnt(0)" ::: "memory");
            __builtin_amdgcn_s_barrier();
            __builtin_amdgcn_sched_barrier(0);
        }
    };

#pragma unroll 1
    for (int j = 0; j < 32; ++j) {
        body(2 * j,     wB, wA);
        body(2 * j + 1, wA, wB);
    }

    int col = lane & 15;
    int rq  = (lane >> 4) * 4;
#pragma unroll
    for (int i = 0; i < 4; i++)
#pragma unroll
        for (int oi = 0; oi < 2; oi++)
#pragma unroll
            for (int r = 0; r < 4; r++) {
                int m = mq * 64 + i * 16 + rq + r;
                int o = o0 + (2 * oh + oi) * 16 + col;
                part[((size_t)ks * 256 + m) * 4096 + o] = acc[i][oi][r];
            }
}

// ----------------------------------------------- K-split reduce + IF for fc1
__global__ void k_fc1_if(const float* __restrict__ part,
                         float* __restrict__ spk3) {
    int idx = blockIdx.x * 256 + threadIdx.x;   // 131072
    int o = idx & 4095;
    int n = idx >> 12;
    float v = 0.f;
    for (int t = 0; t < T_STEPS; t++) {
        int m = t * NB + n;
        float s = 0.f;
#pragma unroll
        for (int ks = 0; ks < 8; ks++)
            s += part[((size_t)ks * 256 + m) * 4096 + o];
        v += s;
        float sp = (v >= 1.f) ? 1.f : 0.f;
        if (sp > 0.f) v = 0.f;
        spk3[(size_t)m * 4096 + o] = sp;
    }
}

// ------------------------------------------------------ fc2 + IF + time-mean
__global__ __launch_bounds__(256) void k_fc2_if_mean(
        const float* __restrict__ spk3, const float* __restrict__ fc2,
        float* __restrict__ out) {
    int b = blockIdx.x;                  // 320 = 32n * 10o
    int n = b / 10, o = b % 10;
    const float* wr = fc2 + o * 4096;
    __shared__ float red[256];
    int tid = threadIdx.x;
    float v = 0.f, cnt = 0.f;
    for (int t = 0; t < T_STEPS; t++) {
        const float* row = spk3 + (size_t)(t * NB + n) * 4096;
        float p = 0.f;
        for (int i = tid; i < 4096; i += 256) p += row[i] * wr[i];
        red[tid] = p;
        __syncthreads();
        for (int s = 128; s > 0; s >>= 1) {
            if (tid < s) red[tid] += red[tid + s];
            __syncthreads();
        }
        if (tid == 0) {
            v += red[0];
            float sp = (v >= 1.f) ? 1.f : 0.f;
            cnt += sp;
            if (sp > 0.f) v = 0.f;
        }
        __syncthreads();
    }
    if (tid == 0) out[n * 10 + o] = cnt * 0.125f;
}

// ---------------------------------------------------------------------- launch
extern "C" void kernel_launch(void* const* d_in, const int* in_sizes, int n_in,
                              void* d_out, int out_size, void* d_ws, size_t ws_size,
                              hipStream_t stream) {
    const float* x   = (const float*)d_in[0];   // [8,32,3,64,64]
    const float* w1  = (const float*)d_in[1];   // [64,3,3,3]
    const float* w2  = (const float*)d_in[2];   // [64,64,3,3]
    const float* fc1 = (const float*)d_in[3];   // [4096,16384]
    const float* fc2 = (const float*)d_in[4];   // [10,4096]
    float* out = (float*)d_out;                 // [32,10]

    float* ws = (float*)d_ws;
    // workspace layout (float slots)
    const size_t off_w2s   = 0;                          // 57344 (110592 bf16)
    const size_t off_spk1p = 57344;                      // 8388608 (16.8M bf16)
    const size_t off_spk2  = off_spk1p + 8388608;        // 2097152 (4.2M bf16)
    const size_t off_part  = off_spk2 + 2097152;         // 8388608
    const size_t off_spk3  = off_part + 8388608;         // 1048576
    __bf16* w2s   = (__bf16*)(ws + off_w2s);
    __bf16* spk1p = (__bf16*)(ws + off_spk1p);
    __bf16* spk2  = (__bf16*)(ws + off_spk2);
    float*  part  = ws + off_part;
    float*  spk3  = ws + off_spk3;

    k_w2s<<<144, 256, 0, stream>>>(w2, w2s);
    k_conv1_if_pool<<<1024, 256, 0, stream>>>(x, w1, spk1p);
    k_conv2_if_pool<<<256, 512, 0, stream>>>((const short*)spk1p,
                                             (const short*)w2s, spk2);
    k_fc1_mfma<<<512, 512, 0, stream>>>((const short*)spk2, fc1, part);
    k_fc1_if<<<512, 256, 0, stream>>>(part, spk3);
    k_fc2_if_mean<<<320, 256, 0, stream>>>(spk3, fc2, out);
}

// Round 12
// 626.143 us; speedup vs baseline: 1.0315x; 1.0010x over previous
//
#include <hip/hip_runtime.h>
#include <hip/hip_bf16.h>

// SNN forward: conv1(3->64,3x3,p1) -> IF -> pool2 -> conv2(64->64) -> IF -> pool2
//              -> fc1(16384->4096) -> IF -> fc2(4096->10) -> IF -> mean over T
// T=8 N=32 IMG=64.
// conv2 and fc1 use bf16 MFMA: spikes are exactly 0/1 (exact in bf16); fp32
// weights are 3-way bf16 split (hi+mid+lo, residual <= 2^-25|w|) -> three MFMAs
// into one fp32 accumulator == fp32 dot product to within fp32 rounding noise.
// conv1: R9 scalar-patch version (R10's shuffle rewrite regressed).
// fc1 (R12): re-tiled waves. 256-thread blocks, 4 waves = 2mq x 2oh, each wave
// owns 128 M-rows (av[8]) x 32 outputs -> 48 MFMA per 14 b128 ds_reads
// (ratio 2.4 -> 3.4); W frag duplication 4x -> 2x; per-CU LDS reads -30%.
// Keeps R9's cooperative W split3 (once per K-step -> pre-split bf16 LDS),
// A slab DMA double-buffer, R11's counted-vmcnt barrier (A-DMAs done,
// W(it+2) register prefetch stays in flight).
// conv2 (R5): A tile (zero-padded, 42.5 KB) DMA-staged per t; inner loop is
// pure ds_read_b128 + MFMA, no bounds checks; 16B-slot swizzle on DMA source.

#define T_STEPS 8
#define NB      32
#define CMID    64

typedef __bf16 bf16x2 __attribute__((ext_vector_type(2)));
typedef __bf16 bf16x4 __attribute__((ext_vector_type(4)));
typedef __bf16 bf16x8 __attribute__((ext_vector_type(8)));
typedef short  s16x4  __attribute__((ext_vector_type(4)));
typedef short  s16x8  __attribute__((ext_vector_type(8)));
typedef float  f32x4  __attribute__((ext_vector_type(4)));

struct Split3 { float h, m, l; };
__device__ __forceinline__ Split3 split3(float x) {
    Split3 s;
    __bf16 h = (__bf16)x;
    float r1 = x - (float)h;
    __bf16 m = (__bf16)r1;
    float r2 = r1 - (float)m;
    __bf16 l = (__bf16)r2;
    s.h = (float)h; s.m = (float)m; s.l = (float)l;
    return s;
}

// split 4 fp32 into three bf16x4 (hi/mid/lo), bit-identical to split3()
__device__ __forceinline__ void split3w4(float4 v, s16x4& fh, s16x4& fm,
                                         s16x4& fl) {
    float x[4] = {v.x, v.y, v.z, v.w};
    s16x4 h, m, l;
#pragma unroll
    for (int j = 0; j < 4; j++) {
        __bf16 ch = (__bf16)x[j];
        float r1 = x[j] - (float)ch;
        __bf16 cm = (__bf16)r1;
        float r2 = r1 - (float)cm;
        __bf16 cl = (__bf16)r2;
        h[j] = __builtin_bit_cast(short, ch);
        m[j] = __builtin_bit_cast(short, cm);
        l[j] = __builtin_bit_cast(short, cl);
    }
    fh = h; fm = m; fl = l;
}

// async global(16B/lane) -> LDS, wave-uniform dest base + lane*16
__device__ __forceinline__ void load_lds16(const void* g, void* l) {
    __builtin_amdgcn_global_load_lds(
        (const __attribute__((address_space(1))) void*)g,
        (__attribute__((address_space(3))) void*)l, 16, 0, 0);
}

// ------------------------------------------------- w2 -> 3-way-split frag order
// w2[co][ci][ky][kx] fp32 -> w2s[ch][tap][kh][oh][sp][lane][j] bf16 where
// co = ch*32+oh*16+(lane&15), ci = kh*32+(lane>>4)*8+j, tap = ky*3+kx.
// This is exactly the MFMA B-fragment order; conv2 blocks memcpy it into LDS.
__global__ void k_w2s(const float* __restrict__ w2, __bf16* __restrict__ w2s) {
    int idx = blockIdx.x * 256 + threadIdx.x;   // 36864 total
    int j    = idx & 7;
    int lane = (idx >> 3) & 63;
    int oh   = (idx >> 9) & 1;
    int kh   = (idx >> 10) & 1;
    int g    = idx >> 11;          // ch*9 + tap, 0..17
    int tap  = g % 9;
    int ch   = g / 9;
    int co = ch * 32 + oh * 16 + (lane & 15);
    int ci = kh * 32 + (lane >> 4) * 8 + j;
    float w = w2[co * 576 + ci * 9 + tap];
    Split3 s = split3(w);
    __bf16* o = w2s + (((size_t)(g * 2 + kh) * 2 + oh) * 3) * 512 + lane * 8 + j;
    o[0]    = (__bf16)s.h;
    o[512]  = (__bf16)s.m;
    o[1024] = (__bf16)s.l;
}

// ------------------------------------------ conv1 + IF + maxpool -> NHWC bf16
// Writes spk1p[tn][h][w][ci] bf16 (ci contiguous -> conv2 A-fragments are
// single 16B loads).
__global__ __launch_bounds__(256) void k_conv1_if_pool(
        const float* __restrict__ x, const float* __restrict__ w1,
        __bf16* __restrict__ spk1p) {
    int b   = blockIdx.x;               // 1024 = 32n * 8cog * 4pht
    int n   = b >> 5;
    int cog = (b >> 2) & 7;
    int pht = b & 3;
    int tid = threadIdx.x;
    int pw  = tid & 31;
    int ph  = pht * 8 + (tid >> 5);
    int ih0 = 2 * ph - 1, iw0 = 2 * pw - 1;

    float v[8][4];
#pragma unroll
    for (int a = 0; a < 8; a++)
#pragma unroll
        for (int p = 0; p < 4; p++) v[a][p] = 0.f;

    for (int t = 0; t < T_STEPS; t++) {
        const float* xb = x + (size_t)(t * NB + n) * 3 * 4096;
        float patch[3][4][4];
#pragma unroll
        for (int ci = 0; ci < 3; ci++)
#pragma unroll
            for (int dy = 0; dy < 4; dy++) {
                int ih = ih0 + dy;
                bool rok = ((unsigned)ih < 64u);
#pragma unroll
                for (int dx = 0; dx < 4; dx++) {
                    int iw = iw0 + dx;
                    patch[ci][dy][dx] = (rok && ((unsigned)iw < 64u))
                                            ? xb[ci * 4096 + ih * 64 + iw] : 0.f;
                }
            }
        bf16x8 sv;
#pragma unroll
        for (int c8 = 0; c8 < 8; c8++) {
            int co = cog * 8 + c8;
            const float* wc = w1 + co * 27;   // wave-uniform -> s_load
            float a0 = 0.f, a1 = 0.f, a2 = 0.f, a3 = 0.f;
#pragma unroll
            for (int ci = 0; ci < 3; ci++)
#pragma unroll
                for (int ky = 0; ky < 3; ky++)
#pragma unroll
                    for (int kx = 0; kx < 3; kx++) {
                        float w = wc[ci * 9 + ky * 3 + kx];
                        a0 += w * patch[ci][ky][kx];
                        a1 += w * patch[ci][ky][kx + 1];
                        a2 += w * patch[ci][ky + 1][kx];
                        a3 += w * patch[ci][ky + 1][kx + 1];
                    }
            float s0, s1, s2, s3;
            v[c8][0] += a0; s0 = (v[c8][0] >= 1.f) ? 1.f : 0.f; if (s0 > 0.f) v[c8][0] = 0.f;
            v[c8][1] += a1; s1 = (v[c8][1] >= 1.f) ? 1.f : 0.f; if (s1 > 0.f) v[c8][1] = 0.f;
            v[c8][2] += a2; s2 = (v[c8][2] >= 1.f) ? 1.f : 0.f; if (s2 > 0.f) v[c8][2] = 0.f;
            v[c8][3] += a3; s3 = (v[c8][3] >= 1.f) ? 1.f : 0.f; if (s3 > 0.f) v[c8][3] = 0.f;
            sv[c8] = (__bf16)fmaxf(fmaxf(s0, s1), fmaxf(s2, s3));
        }
        *(bf16x8*)(spk1p + ((size_t)(t * NB + n) * 1024 + ph * 32 + pw) * 64
                         + cog * 8) = sv;
    }
}

// -------------------------------- conv2 (MFMA) + IF + maxpool fused, t in-kernel
// 8 waves (mh 0..3 x oh 0..1) covering 2 strips; grid 256 = 1 block/CU.
// A tile [10 rows][34 w (zero-padded)][8 slots of 16B] DMA-staged per t;
// slot swizzle: phys = logical ^ (widx&7), inverse applied on DMA source.
__global__ __launch_bounds__(512, 2) void k_conv2_if_pool(
        const short* __restrict__ spk1p,   // [256][32][32][64] bf16 bits
        const short* __restrict__ w2s,     // [2][55296] bf16 bits (frag order)
        __bf16* __restrict__ spk2) {       // [256][64][16][16]
    int b     = blockIdx.x;                // 256 = 32n * 4s2 * 2ch
    int ch    = b & 1;
    int s2    = (b >> 1) & 3;
    int n     = b >> 3;
    int tid   = threadIdx.x;
    int lane  = tid & 63;
    int wv    = tid >> 6;                  // 0..7
    int mh    = wv >> 1, oh = wv & 1;      // mh 0..3
    int lm    = lane & 15, kq = lane >> 4;

    __shared__ short Bs[55296];            // 108 KB: 9tap x 2kh x 2oh x 3sp x 512
    __shared__ short As[10 * 34 * 64];     // 42.5 KB: [r][widx][8 slots x 8 shorts]

    {
        const uint4* src = (const uint4*)(w2s + (size_t)ch * 55296);
        uint4* dst = (uint4*)Bs;
        for (int i = tid; i < 6912; i += 512) dst[i] = src[i];
        // zero whole A tile once: pad cols (widx 0,33) + out-of-image rows
        // stay zero forever (DMA never writes them).
        uint4* za = (uint4*)As;
        for (int i = tid; i < 2720; i += 512) za[i] = (uint4){0, 0, 0, 0};
    }
    __syncthreads();
    const short* Bsw = Bs + oh * 1536;

    int wl  = lane >> 3;
    int sph = lane & 7;

    f32x4 v[4];
#pragma unroll
    for (int i = 0; i < 4; i++) v[i] = (f32x4){0.f, 0.f, 0.f, 0.f};

    int co = ch * 32 + oh * 16 + lm;
    int pH = s2 * 4 + mh;

#pragma unroll 1
    for (int t = 0; t < T_STEPS; t++) {
        const short* img = spk1p + (size_t)(t * NB + n) * 65536;

        if (t > 0) __syncthreads();        // all reads of As[t-1] done
#pragma unroll
        for (int q = 0; q < 5; q++) {
            int u = q * 8 + wv;            // 0..39, wave-uniform
            int r = u >> 2;
            int quarter = u & 3;
            int hh = s2 * 8 - 1 + r;
            if ((unsigned)hh < 32u) {
                int widx = quarter * 8 + 1 + wl;
                int slog = sph ^ (widx & 7);
                const short* src = img + (size_t)(hh * 32 + widx - 1) * 64
                                       + slog * 8;
                short* dst = As + (r * 34 + quarter * 8 + 1) * 64;
                load_lds16(src, dst);
            }
        }
        __syncthreads();                   // drains DMA (vmcnt 0): As[t] ready

        f32x4 acc[4];
#pragma unroll
        for (int i = 0; i < 4; i++) acc[i] = (f32x4){0.f, 0.f, 0.f, 0.f};

#pragma unroll 1
        for (int dy = 0; dy < 3; dy++) {
#pragma unroll 1
            for (int dx = 0; dx < 3; dx++) {
                const short* bp = Bsw + (dy * 3 + dx) * 6144 + lane * 8;
                s16x8 bf[2][3];
#pragma unroll
                for (int kh = 0; kh < 2; kh++)
#pragma unroll
                    for (int sp = 0; sp < 3; sp++)
                        bf[kh][sp] = *(const s16x8*)(bp + kh * 3072 + sp * 512);
#pragma unroll
                for (int i = 0; i < 4; i++) {
                    int r    = 2 * mh + (i >> 1) + dy;              // 0..9
                    int widx = (i & 1) * 16 + lm + dx;              // 0..33
                    const short* ap = As + (r * 34 + widx) * 64;
                    s16x8 a0 = *(const s16x8*)(ap + ((kq    ) ^ (widx & 7)) * 8);
                    s16x8 a1 = *(const s16x8*)(ap + ((kq + 4) ^ (widx & 7)) * 8);
#pragma unroll
                    for (int sp = 0; sp < 3; sp++) {
                        acc[i] = __builtin_amdgcn_mfma_f32_16x16x32_bf16(
                            a0, bf[0][sp], acc[i], 0, 0, 0);
                        acc[i] = __builtin_amdgcn_mfma_f32_16x16x32_bf16(
                            a1, bf[1][sp], acc[i], 0, 0, 0);
                    }
                }
            }
        }
        // IF (charge, fire, hard reset) then 2x2 max-pool, all within-lane
        float s[4][4];
#pragma unroll
        for (int i = 0; i < 4; i++)
#pragma unroll
            for (int r = 0; r < 4; r++) {
                float vv = v[i][r] + acc[i][r];
                float sp = (vv >= 1.f) ? 1.f : 0.f;
                s[i][r] = sp;
                v[i][r] = (sp > 0.f) ? 0.f : vv;
            }
        __bf16* op = spk2 + ((size_t)(t * NB + n) * 64 + co) * 256 + pH * 16
                   + kq * 2;
#pragma unroll
        for (int i2 = 0; i2 < 2; i2++) {
            float p0 = fmaxf(fmaxf(s[i2][0], s[i2][1]),
                             fmaxf(s[i2 + 2][0], s[i2 + 2][1]));
            float p1 = fmaxf(fmaxf(s[i2][2], s[i2][3]),
                             fmaxf(s[i2 + 2][2], s[i2 + 2][3]));
            bf16x2 pv = {(__bf16)p0, (__bf16)p1};
            *(bf16x2*)(op + i2 * 8) = pv;
        }
    }
}

// ----------------------------------------------------------- fc1 via bf16 MFMA
// R12: 256-thread blocks (4 waves: mq 0..1 x oh 0..1), grid 512 = 2 blocks/CU.
// Each wave owns 128 M-rows (av[8]) x 32 outputs -> 48 MFMA per 14 b128 reads
// (was 24 per 10); W frag duplication 4x->2x, A 2x. Per K-step(32):
//   A slab (256 x 32k bf16, 16 KB) DMA double-buffered (swizzle
//     slot ^= ((r>>1)&3) on DMA source + reads).
//   W slab split ONCE cooperatively: each thread loads 2 float4 of W fp32
//     (row=tid>>2, k=(tid&3)*8), split3 x8, writes 6x bf16x4 into
//     Wbf[buf][sp][64][32] (16B-chunk swizzle kc ^= ((row>>1)&3)).
//   Counted-vmcnt barrier: end-of-body s_waitcnt vmcnt(2) lgkmcnt(0) ->
//   A(it+1) DMAs done + Wbf writes visible; W(it+2) reg loads in flight.
// Same split3 bits + same per-element k-order -> bit-identical output.
// LDS = 32 KB (A) + 24 KB (Wbf) = 56 KB -> 2 blocks/CU, 2 waves/SIMD.
__global__ __launch_bounds__(256, 2) void k_fc1_mfma(
        const short* __restrict__ A,      // spk2 bf16 bits [256][16384]
        const float* __restrict__ W,      // fc1 [4096][16384]
        float* __restrict__ part) {       // [8][256][4096]
    int b  = blockIdx.x;                  // 512 = 64nt * 8ks
    int nt = b & 63;
    int ks = b >> 6;
    int o0 = nt * 64;
    int kbase = ks * 2048;

    int tid  = threadIdx.x;
    int lane = tid & 63;
    int wv   = tid >> 6;                  // 0..3
    int mq   = wv >> 1;                   // M half (128 rows)
    int oh   = wv & 1;                    // output half (32 of 64)
    int lm   = lane & 15;
    int kq   = lane >> 4;

    __shared__ short Asm[2][8192];        // 2 x 16 KB A slab (swizzled)
    __shared__ short Wbf[2][6144];        // 2 x 12 KB pre-split W bf16
                                          //   [sp][row 64][chunk 4 x 8 shorts]

    // A DMA source (inverse swizzle on source; dest linear):
    // phys unit p = q*256+tid: r=p>>2, slot=(p&3)^((r>>1)&3)
    const short* gA[4];
#pragma unroll
    for (int q = 0; q < 4; q++) {
        int p = q * 256 + tid;
        int r = p >> 2;
        int c = (p & 3) ^ ((r >> 1) & 3);
        gA[q] = A + (size_t)r * 16384 + kbase + c * 8;
    }

    // W global load: thread covers row=tid>>2 (o0+row), k8=(tid&3)*8 (2 f4)
    int wrow = tid >> 2;                  // 0..63
    const float* gWf = W + (size_t)(o0 + wrow) * 16384 + kbase + (tid & 3) * 8;

    // W bf16 write offset (shorts): row*32 + physchunk*8 + half*4 (+ sp*2048)
    int wkc   = tid & 3;                  // chunk
    int wwoff = wrow * 32 + (wkc ^ ((wrow >> 1) & 3)) * 8;   // + f*4

    // LDS read offsets (swizzled)
    int aoff[8];                          // shorts
#pragma unroll
    for (int i = 0; i < 8; i++) {
        int r = mq * 128 + i * 16 + lm;
        aoff[i] = (r * 4 + (kq ^ ((r >> 1) & 3))) * 8;
    }
    int wroff[2];                         // shorts (+ sp*2048)
#pragma unroll
    for (int oi = 0; oi < 2; oi++) {
        int row = (2 * oh + oi) * 16 + lm;
        wroff[oi] = row * 32 + (kq ^ ((row >> 1) & 3)) * 8;
    }

    f32x4 acc[8][2];
#pragma unroll
    for (int i = 0; i < 8; i++)
#pragma unroll
        for (int oi = 0; oi < 2; oi++) acc[i][oi] = (f32x4){0.f, 0.f, 0.f, 0.f};

    // prologue: W(0) 2xf4 load+split -> Wbf[0]; W(1) into regs; A(0) DMA
    float4 wA0 = *(const float4*)gWf;         // W it=0
    float4 wA1 = *(const float4*)(gWf + 4);
#pragma unroll
    for (int q = 0; q < 4; q++)
        load_lds16(gA[q], &Asm[0][q * 2048 + wv * 512]);
    {
        s16x4 h4, m4, l4;
        split3w4(wA0, h4, m4, l4);
        *(s16x4*)&Wbf[0][wwoff]            = h4;
        *(s16x4*)&Wbf[0][2048 + wwoff]     = m4;
        *(s16x4*)&Wbf[0][4096 + wwoff]     = l4;
        split3w4(wA1, h4, m4, l4);
        *(s16x4*)&Wbf[0][wwoff + 4]        = h4;
        *(s16x4*)&Wbf[0][2048 + wwoff + 4] = m4;
        *(s16x4*)&Wbf[0][4096 + wwoff + 4] = l4;
    }
    float4 wB0 = *(const float4*)(gWf + 32);  // W it=1
    float4 wB1 = *(const float4*)(gWf + 36);
    asm volatile("s_waitcnt vmcnt(2) lgkmcnt(0)" ::: "memory");
    __builtin_amdgcn_s_barrier();
    __builtin_amdgcn_sched_barrier(0);

    // body: ws0/ws1 hold W(it+1) fp32; wl0/wl1 receive W(it+2)
    auto body = [&](int it, float4& ws0, float4& ws1, float4& wl0,
                    float4& wl1) {
        int nb = (it + 1) & 1;
        if (it < 63) {
            // A-DMA for it+1 issued FIRST (oldest in vm queue)
#pragma unroll
            for (int q = 0; q < 4; q++)
                load_lds16(gA[q] + (it + 1) * 32,
                           &Asm[nb][q * 2048 + wv * 512]);
            __builtin_amdgcn_sched_barrier(0);   // pin: DMAs before wload
            s16x4 h4, m4, l4;
            split3w4(ws0, h4, m4, l4);
            *(s16x4*)&Wbf[nb][wwoff]            = h4;
            *(s16x4*)&Wbf[nb][2048 + wwoff]     = m4;
            *(s16x4*)&Wbf[nb][4096 + wwoff]     = l4;
            split3w4(ws1, h4, m4, l4);
            *(s16x4*)&Wbf[nb][wwoff + 4]        = h4;
            *(s16x4*)&Wbf[nb][2048 + wwoff + 4] = m4;
            *(s16x4*)&Wbf[nb][4096 + wwoff + 4] = l4;
        }
        if (it < 62) {
            wl0 = *(const float4*)(gWf + (it + 2) * 32);
            wl1 = *(const float4*)(gWf + (it + 2) * 32 + 4);
            __builtin_amdgcn_sched_barrier(0);   // pin: wload issued here
        }

        const short* as = Asm[it & 1];
        const short* wb = Wbf[it & 1];
        s16x8 av[8];
#pragma unroll
        for (int i = 0; i < 8; i++)
            av[i] = *(const s16x8*)(as + aoff[i]);
        s16x8 bfr[3][2];                  // [sp][oi]
#pragma unroll
        for (int oi = 0; oi < 2; oi++)
#pragma unroll
            for (int sp = 0; sp < 3; sp++)
                bfr[sp][oi] = *(const s16x8*)(wb + sp * 2048 + wroff[oi]);

#pragma unroll
        for (int i = 0; i < 8; i++)
#pragma unroll
            for (int oi = 0; oi < 2; oi++) {
                acc[i][oi] = __builtin_amdgcn_mfma_f32_16x16x32_bf16(
                    av[i], bfr[0][oi], acc[i][oi], 0, 0, 0);
                acc[i][oi] = __builtin_amdgcn_mfma_f32_16x16x32_bf16(
                    av[i], bfr[1][oi], acc[i][oi], 0, 0, 0);
                acc[i][oi] = __builtin_amdgcn_mfma_f32_16x16x32_bf16(
                    av[i], bfr[2][oi], acc[i][oi], 0, 0, 0);
            }

        // counted sync: A(it+1) DMAs done + ds_writes visible; W(it+2)
        // register loads stay in flight across the barrier.
        if (it < 62) {
            asm volatile("s_waitcnt vmcnt(2) lgkmcnt(0)" ::: "memory");
            __builtin_amdgcn_s_barrier();
            __builtin_amdgcn_sched_barrier(0);
        } else if (it == 62) {
            asm volatile("s_waitcnt vmcnt(0) lgkmcnt(0)" ::: "memory");
            __builtin_amdgcn_s_barrier();
            __builtin_amdgcn_sched_barrier(0);
        }
    };

#pragma unroll 1
    for (int j = 0; j < 32; ++j) {
        body(2 * j,     wB0, wB1, wA0, wA1);
        body(2 * j + 1, wA0, wA1, wB0, wB1);
    }

    int col = lane & 15;
    int rq  = (lane >> 4) * 4;
#pragma unroll
    for (int i = 0; i < 8; i++)
#pragma unroll
        for (int oi = 0; oi < 2; oi++)
#pragma unroll
            for (int r = 0; r < 4; r++) {
                int m = mq * 128 + i * 16 + rq + r;
                int o = o0 + (2 * oh + oi) * 16 + col;
                part[((size_t)ks * 256 + m) * 4096 + o] = acc[i][oi][r];
            }
}

// ----------------------------------------------- K-split reduce + IF for fc1
__global__ void k_fc1_if(const float* __restrict__ part,
                         float* __restrict__ spk3) {
    int idx = blockIdx.x * 256 + threadIdx.x;   // 131072
    int o = idx & 4095;
    int n = idx >> 12;
    float v = 0.f;
    for (int t = 0; t < T_STEPS; t++) {
        int m = t * NB + n;
        float s = 0.f;
#pragma unroll
        for (int ks = 0; ks < 8; ks++)
            s += part[((size_t)ks * 256 + m) * 4096 + o];
        v += s;
        float sp = (v >= 1.f) ? 1.f : 0.f;
        if (sp > 0.f) v = 0.f;
        spk3[(size_t)m * 4096 + o] = sp;
    }
}

// ------------------------------------------------------ fc2 + IF + time-mean
__global__ __launch_bounds__(256) void k_fc2_if_mean(
        const float* __restrict__ spk3, const float* __restrict__ fc2,
        float* __restrict__ out) {
    int b = blockIdx.x;                  // 320 = 32n * 10o
    int n = b / 10, o = b % 10;
    const float* wr = fc2 + o * 4096;
    __shared__ float red[256];
    int tid = threadIdx.x;
    float v = 0.f, cnt = 0.f;
    for (int t = 0; t < T_STEPS; t++) {
        const float* row = spk3 + (size_t)(t * NB + n) * 4096;
        float p = 0.f;
        for (int i = tid; i < 4096; i += 256) p += row[i] * wr[i];
        red[tid] = p;
        __syncthreads();
        for (int s = 128; s > 0; s >>= 1) {
            if (tid < s) red[tid] += red[tid + s];
            __syncthreads();
        }
        if (tid == 0) {
            v += red[0];
            float sp = (v >= 1.f) ? 1.f : 0.f;
            cnt += sp;
            if (sp > 0.f) v = 0.f;
        }
        __syncthreads();
    }
    if (tid == 0) out[n * 10 + o] = cnt * 0.125f;
}

// ---------------------------------------------------------------------- launch
extern "C" void kernel_launch(void* const* d_in, const int* in_sizes, int n_in,
                              void* d_out, int out_size, void* d_ws, size_t ws_size,
                              hipStream_t stream) {
    const float* x   = (const float*)d_in[0];   // [8,32,3,64,64]
    const float* w1  = (const float*)d_in[1];   // [64,3,3,3]
    const float* w2  = (const float*)d_in[2];   // [64,64,3,3]
    const float* fc1 = (const float*)d_in[3];   // [4096,16384]
    const float* fc2 = (const float*)d_in[4];   // [10,4096]
    float* out = (float*)d_out;                 // [32,10]

    float* ws = (float*)d_ws;
    // workspace layout (float slots)
    const size_t off_w2s   = 0;                          // 57344 (110592 bf16)
    const size_t off_spk1p = 57344;                      // 8388608 (16.8M bf16)
    const size_t off_spk2  = off_spk1p + 8388608;        // 2097152 (4.2M bf16)
    const size_t off_part  = off_spk2 + 2097152;         // 8388608
    const size_t off_spk3  = off_part + 8388608;         // 1048576
    __bf16* w2s   = (__bf16*)(ws + off_w2s);
    __bf16* spk1p = (__bf16*)(ws + off_spk1p);
    __bf16* spk2  = (__bf16*)(ws + off_spk2);
    float*  part  = ws + off_part;
    float*  spk3  = ws + off_spk3;

    k_w2s<<<144, 256, 0, stream>>>(w2, w2s);
    k_conv1_if_pool<<<1024, 256, 0, stream>>>(x, w1, spk1p);
    k_conv2_if_pool<<<256, 512, 0, stream>>>((const short*)spk1p,
                                             (const short*)w2s, spk2);
    k_fc1_mfma<<<512, 256, 0, stream>>>((const short*)spk2, fc1, part);
    k_fc1_if<<<512, 256, 0, stream>>>(part, spk3);
    k_fc2_if_mean<<<320, 256, 0, stream>>>(spk3, fc2, out);
}

// Round 13
// 623.358 us; speedup vs baseline: 1.0361x; 1.0045x over previous
//
#include <hip/hip_runtime.h>
#include <hip/hip_bf16.h>

// SNN forward: conv1(3->64,3x3,p1) -> IF -> pool2 -> conv2(64->64) -> IF -> pool2
//              -> fc1(16384->4096) -> IF -> fc2(4096->10) -> IF -> mean over T
// T=8 N=32 IMG=64.
// conv2 and fc1 use bf16 MFMA: spikes are exactly 0/1 (exact in bf16); fp32
// weights are 3-way bf16 split (hi+mid+lo, residual <= 2^-25|w|) -> three MFMAs
// into one fp32 accumulator == fp32 dot product to within fp32 rounding noise.
// conv1 (R13): was 48 bounds-checked per-lane global loads per t (47% stall,
// VALUBusy 53%, ~161us in R12 counters). Now the 3x18x64 fp32 x-tile (13.8 KB)
// is DMA-staged into double-buffered LDS (15 global_load_lds issues/t, staged
// one t ahead, drained by the end-of-t barrier). Patch reads: aligned
// ds_read_b64 middle pair + 2 clamped/masked halo scalars; OOB rows
// pre-zeroed -> values bit-identical to the old bounds-checked loads.
// fc1 (R12): 4-wave blocks, wave = 128 M-rows x 32 outs; cooperative W split3
// once per K-step -> pre-split bf16 LDS; A slab DMA double-buffer;
// counted-vmcnt barrier.
// conv2 (R5): A tile (zero-padded, 42.5 KB) DMA-staged per t; inner loop is
// pure ds_read_b128 + MFMA, no bounds checks; 16B-slot swizzle on DMA source.

#define T_STEPS 8
#define NB      32
#define CMID    64

typedef __bf16 bf16x2 __attribute__((ext_vector_type(2)));
typedef __bf16 bf16x4 __attribute__((ext_vector_type(4)));
typedef __bf16 bf16x8 __attribute__((ext_vector_type(8)));
typedef short  s16x4  __attribute__((ext_vector_type(4)));
typedef short  s16x8  __attribute__((ext_vector_type(8)));
typedef float  f32x4  __attribute__((ext_vector_type(4)));

struct Split3 { float h, m, l; };
__device__ __forceinline__ Split3 split3(float x) {
    Split3 s;
    __bf16 h = (__bf16)x;
    float r1 = x - (float)h;
    __bf16 m = (__bf16)r1;
    float r2 = r1 - (float)m;
    __bf16 l = (__bf16)r2;
    s.h = (float)h; s.m = (float)m; s.l = (float)l;
    return s;
}

// split 4 fp32 into three bf16x4 (hi/mid/lo), bit-identical to split3()
__device__ __forceinline__ void split3w4(float4 v, s16x4& fh, s16x4& fm,
                                         s16x4& fl) {
    float x[4] = {v.x, v.y, v.z, v.w};
    s16x4 h, m, l;
#pragma unroll
    for (int j = 0; j < 4; j++) {
        __bf16 ch = (__bf16)x[j];
        float r1 = x[j] - (float)ch;
        __bf16 cm = (__bf16)r1;
        float r2 = r1 - (float)cm;
        __bf16 cl = (__bf16)r2;
        h[j] = __builtin_bit_cast(short, ch);
        m[j] = __builtin_bit_cast(short, cm);
        l[j] = __builtin_bit_cast(short, cl);
    }
    fh = h; fm = m; fl = l;
}

// async global(16B/lane) -> LDS, wave-uniform dest base + lane*16
__device__ __forceinline__ void load_lds16(const void* g, void* l) {
    __builtin_amdgcn_global_load_lds(
        (const __attribute__((address_space(1))) void*)g,
        (__attribute__((address_space(3))) void*)l, 16, 0, 0);
}

// ------------------------------------------------- w2 -> 3-way-split frag order
__global__ void k_w2s(const float* __restrict__ w2, __bf16* __restrict__ w2s) {
    int idx = blockIdx.x * 256 + threadIdx.x;   // 36864 total
    int j    = idx & 7;
    int lane = (idx >> 3) & 63;
    int oh   = (idx >> 9) & 1;
    int kh   = (idx >> 10) & 1;
    int g    = idx >> 11;          // ch*9 + tap, 0..17
    int tap  = g % 9;
    int ch   = g / 9;
    int co = ch * 32 + oh * 16 + (lane & 15);
    int ci = kh * 32 + (lane >> 4) * 8 + j;
    float w = w2[co * 576 + ci * 9 + tap];
    Split3 s = split3(w);
    __bf16* o = w2s + (((size_t)(g * 2 + kh) * 2 + oh) * 3) * 512 + lane * 8 + j;
    o[0]    = (__bf16)s.h;
    o[512]  = (__bf16)s.m;
    o[1024] = (__bf16)s.l;
}

// ------------------------------------------ conv1 + IF + maxpool -> NHWC bf16
// x tile DMA-staged in LDS, double-buffered across t. Patch values are
// bit-identical to the old bounds-checked global loads (OOB rows pre-zeroed,
// pw==0/31 halo cols masked).
__global__ __launch_bounds__(256) void k_conv1_if_pool(
        const float* __restrict__ x, const float* __restrict__ w1,
        __bf16* __restrict__ spk1p) {
    int b    = blockIdx.x;              // 1024 = 32n * 8cog * 4pht
    int n    = b >> 5;
    int cog  = (b >> 2) & 7;
    int pht  = b & 3;
    int tid  = threadIdx.x;
    int pw   = tid & 31;
    int phl  = tid >> 5;                // 0..7 (local pooled row)
    int wv   = tid >> 6;                // 0..3
    int lane = tid & 63;

    // tile row tr <-> global row gr = 16*pht - 1 + tr, tr in [0,17]
    __shared__ float Xt[2][3][18][64];  // 27.6 KB

    {   // zero both buffers once (covers never-DMA'd OOB rows for pht 0/3)
        float* xz = &Xt[0][0][0][0];
        for (int i = tid; i < 6912; i += 256) xz[i] = 0.f;
    }

    int trlo = (pht == 0) ? 1 : 0;      // valid tile rows [trlo, trhi]
    int trhi = (pht == 3) ? 16 : 17;

    // stage x[t] tile into Xt[buf]: 15 wave-uniform 4-row (1 KB) issues,
    // last issue per ci overlaps to cover the 17/18-row range exactly.
    auto stage = [&](int t, int buf) {
        const float* xb = x + (size_t)(t * NB + n) * 3 * 4096;
        for (int i = wv; i < 15; i += 4) {
            int ci  = i / 5, q = i % 5;
            int tr0 = (q < 4) ? (trlo + 4 * q) : (trhi - 3);
            int gr0 = 16 * pht - 1 + tr0;
            const float* src = xb + ci * 4096 + (gr0 + (lane >> 4)) * 64
                             + (lane & 15) * 4;
            load_lds16(src, &Xt[buf][ci][tr0][0]);
        }
    };

    __syncthreads();
    stage(0, 0);
    __syncthreads();

    bool pw0  = (pw == 0);
    bool pw31 = (pw == 31);
    int  cl   = pw0 ? 0 : (2 * pw - 1);   // clamped halo cols
    int  cr   = pw31 ? 63 : (2 * pw + 2);

    float v[8][4];
#pragma unroll
    for (int a = 0; a < 8; a++)
#pragma unroll
        for (int p = 0; p < 4; p++) v[a][p] = 0.f;

    for (int t = 0; t < T_STEPS; t++) {
        int buf = t & 1;
        if (t < T_STEPS - 1) stage(t + 1, buf ^ 1);

        float patch[3][4][4];
#pragma unroll
        for (int ci = 0; ci < 3; ci++)
#pragma unroll
            for (int dy = 0; dy < 4; dy++) {
                int tr = 2 * phl + dy;                  // 0..17
                const float* row = &Xt[buf][ci][tr][0];
                float2 mid = *(const float2*)(row + 2 * pw);
                float lv = row[cl];
                float rv = row[cr];
                patch[ci][dy][0] = pw0 ? 0.f : lv;
                patch[ci][dy][1] = mid.x;
                patch[ci][dy][2] = mid.y;
                patch[ci][dy][3] = pw31 ? 0.f : rv;
            }
        bf16x8 sv;
#pragma unroll
        for (int c8 = 0; c8 < 8; c8++) {
            int co = cog * 8 + c8;
            const float* wc = w1 + co * 27;   // wave-uniform -> s_load
            float a0 = 0.f, a1 = 0.f, a2 = 0.f, a3 = 0.f;
#pragma unroll
            for (int ci = 0; ci < 3; ci++)
#pragma unroll
                for (int ky = 0; ky < 3; ky++)
#pragma unroll
                    for (int kx = 0; kx < 3; kx++) {
                        float w = wc[ci * 9 + ky * 3 + kx];
                        a0 += w * patch[ci][ky][kx];
                        a1 += w * patch[ci][ky][kx + 1];
                        a2 += w * patch[ci][ky + 1][kx];
                        a3 += w * patch[ci][ky + 1][kx + 1];
                    }
            float s0, s1, s2, s3;
            v[c8][0] += a0; s0 = (v[c8][0] >= 1.f) ? 1.f : 0.f; if (s0 > 0.f) v[c8][0] = 0.f;
            v[c8][1] += a1; s1 = (v[c8][1] >= 1.f) ? 1.f : 0.f; if (s1 > 0.f) v[c8][1] = 0.f;
            v[c8][2] += a2; s2 = (v[c8][2] >= 1.f) ? 1.f : 0.f; if (s2 > 0.f) v[c8][2] = 0.f;
            v[c8][3] += a3; s3 = (v[c8][3] >= 1.f) ? 1.f : 0.f; if (s3 > 0.f) v[c8][3] = 0.f;
            sv[c8] = (__bf16)fmaxf(fmaxf(s0, s1), fmaxf(s2, s3));
        }
        *(bf16x8*)(spk1p + ((size_t)(t * NB + n) * 1024
                            + (pht * 8 + phl) * 32 + pw) * 64 + cog * 8) = sv;

        __syncthreads();   // drains DMA (t+1 tile ready) + guards buf reuse
    }
}

// -------------------------------- conv2 (MFMA) + IF + maxpool fused, t in-kernel
__global__ __launch_bounds__(512, 2) void k_conv2_if_pool(
        const short* __restrict__ spk1p,   // [256][32][32][64] bf16 bits
        const short* __restrict__ w2s,     // [2][55296] bf16 bits (frag order)
        __bf16* __restrict__ spk2) {       // [256][64][16][16]
    int b     = blockIdx.x;                // 256 = 32n * 4s2 * 2ch
    int ch    = b & 1;
    int s2    = (b >> 1) & 3;
    int n     = b >> 3;
    int tid   = threadIdx.x;
    int lane  = tid & 63;
    int wv    = tid >> 6;                  // 0..7
    int mh    = wv >> 1, oh = wv & 1;      // mh 0..3
    int lm    = lane & 15, kq = lane >> 4;

    __shared__ short Bs[55296];            // 108 KB: 9tap x 2kh x 2oh x 3sp x 512
    __shared__ short As[10 * 34 * 64];     // 42.5 KB

    {
        const uint4* src = (const uint4*)(w2s + (size_t)ch * 55296);
        uint4* dst = (uint4*)Bs;
        for (int i = tid; i < 6912; i += 512) dst[i] = src[i];
        uint4* za = (uint4*)As;
        for (int i = tid; i < 2720; i += 512) za[i] = (uint4){0, 0, 0, 0};
    }
    __syncthreads();
    const short* Bsw = Bs + oh * 1536;

    int wl  = lane >> 3;
    int sph = lane & 7;

    f32x4 v[4];
#pragma unroll
    for (int i = 0; i < 4; i++) v[i] = (f32x4){0.f, 0.f, 0.f, 0.f};

    int co = ch * 32 + oh * 16 + lm;
    int pH = s2 * 4 + mh;

#pragma unroll 1
    for (int t = 0; t < T_STEPS; t++) {
        const short* img = spk1p + (size_t)(t * NB + n) * 65536;

        if (t > 0) __syncthreads();
#pragma unroll
        for (int q = 0; q < 5; q++) {
            int u = q * 8 + wv;            // 0..39, wave-uniform
            int r = u >> 2;
            int quarter = u & 3;
            int hh = s2 * 8 - 1 + r;
            if ((unsigned)hh < 32u) {
                int widx = quarter * 8 + 1 + wl;
                int slog = sph ^ (widx & 7);
                const short* src = img + (size_t)(hh * 32 + widx - 1) * 64
                                       + slog * 8;
                short* dst = As + (r * 34 + quarter * 8 + 1) * 64;
                load_lds16(src, dst);
            }
        }
        __syncthreads();                   // drains DMA: As[t] ready

        f32x4 acc[4];
#pragma unroll
        for (int i = 0; i < 4; i++) acc[i] = (f32x4){0.f, 0.f, 0.f, 0.f};

#pragma unroll 1
        for (int dy = 0; dy < 3; dy++) {
#pragma unroll 1
            for (int dx = 0; dx < 3; dx++) {
                const short* bp = Bsw + (dy * 3 + dx) * 6144 + lane * 8;
                s16x8 bf[2][3];
#pragma unroll
                for (int kh = 0; kh < 2; kh++)
#pragma unroll
                    for (int sp = 0; sp < 3; sp++)
                        bf[kh][sp] = *(const s16x8*)(bp + kh * 3072 + sp * 512);
#pragma unroll
                for (int i = 0; i < 4; i++) {
                    int r    = 2 * mh + (i >> 1) + dy;              // 0..9
                    int widx = (i & 1) * 16 + lm + dx;              // 0..33
                    const short* ap = As + (r * 34 + widx) * 64;
                    s16x8 a0 = *(const s16x8*)(ap + ((kq    ) ^ (widx & 7)) * 8);
                    s16x8 a1 = *(const s16x8*)(ap + ((kq + 4) ^ (widx & 7)) * 8);
#pragma unroll
                    for (int sp = 0; sp < 3; sp++) {
                        acc[i] = __builtin_amdgcn_mfma_f32_16x16x32_bf16(
                            a0, bf[0][sp], acc[i], 0, 0, 0);
                        acc[i] = __builtin_amdgcn_mfma_f32_16x16x32_bf16(
                            a1, bf[1][sp], acc[i], 0, 0, 0);
                    }
                }
            }
        }
        float s[4][4];
#pragma unroll
        for (int i = 0; i < 4; i++)
#pragma unroll
            for (int r = 0; r < 4; r++) {
                float vv = v[i][r] + acc[i][r];
                float sp = (vv >= 1.f) ? 1.f : 0.f;
                s[i][r] = sp;
                v[i][r] = (sp > 0.f) ? 0.f : vv;
            }
        __bf16* op = spk2 + ((size_t)(t * NB + n) * 64 + co) * 256 + pH * 16
                   + kq * 2;
#pragma unroll
        for (int i2 = 0; i2 < 2; i2++) {
            float p0 = fmaxf(fmaxf(s[i2][0], s[i2][1]),
                             fmaxf(s[i2 + 2][0], s[i2 + 2][1]));
            float p1 = fmaxf(fmaxf(s[i2][2], s[i2][3]),
                             fmaxf(s[i2 + 2][2], s[i2 + 2][3]));
            bf16x2 pv = {(__bf16)p0, (__bf16)p1};
            *(bf16x2*)(op + i2 * 8) = pv;
        }
    }
}

// ----------------------------------------------------------- fc1 via bf16 MFMA
__global__ __launch_bounds__(256, 2) void k_fc1_mfma(
        const short* __restrict__ A,      // spk2 bf16 bits [256][16384]
        const float* __restrict__ W,      // fc1 [4096][16384]
        float* __restrict__ part) {       // [8][256][4096]
    int b  = blockIdx.x;                  // 512 = 64nt * 8ks
    int nt = b & 63;
    int ks = b >> 6;
    int o0 = nt * 64;
    int kbase = ks * 2048;

    int tid  = threadIdx.x;
    int lane = tid & 63;
    int wv   = tid >> 6;                  // 0..3
    int mq   = wv >> 1;                   // M half (128 rows)
    int oh   = wv & 1;                    // output half (32 of 64)
    int lm   = lane & 15;
    int kq   = lane >> 4;

    __shared__ short Asm[2][8192];        // 2 x 16 KB A slab (swizzled)
    __shared__ short Wbf[2][6144];        // 2 x 12 KB pre-split W bf16

    const short* gA[4];
#pragma unroll
    for (int q = 0; q < 4; q++) {
        int p = q * 256 + tid;
        int r = p >> 2;
        int c = (p & 3) ^ ((r >> 1) & 3);
        gA[q] = A + (size_t)r * 16384 + kbase + c * 8;
    }

    int wrow = tid >> 2;                  // 0..63
    const float* gWf = W + (size_t)(o0 + wrow) * 16384 + kbase + (tid & 3) * 8;

    int wkc   = tid & 3;
    int wwoff = wrow * 32 + (wkc ^ ((wrow >> 1) & 3)) * 8;

    int aoff[8];
#pragma unroll
    for (int i = 0; i < 8; i++) {
        int r = mq * 128 + i * 16 + lm;
        aoff[i] = (r * 4 + (kq ^ ((r >> 1) & 3))) * 8;
    }
    int wroff[2];
#pragma unroll
    for (int oi = 0; oi < 2; oi++) {
        int row = (2 * oh + oi) * 16 + lm;
        wroff[oi] = row * 32 + (kq ^ ((row >> 1) & 3)) * 8;
    }

    f32x4 acc[8][2];
#pragma unroll
    for (int i = 0; i < 8; i++)
#pragma unroll
        for (int oi = 0; oi < 2; oi++) acc[i][oi] = (f32x4){0.f, 0.f, 0.f, 0.f};

    float4 wA0 = *(const float4*)gWf;         // W it=0
    float4 wA1 = *(const float4*)(gWf + 4);
#pragma unroll
    for (int q = 0; q < 4; q++)
        load_lds16(gA[q], &Asm[0][q * 2048 + wv * 512]);
    {
        s16x4 h4, m4, l4;
        split3w4(wA0, h4, m4, l4);
        *(s16x4*)&Wbf[0][wwoff]            = h4;
        *(s16x4*)&Wbf[0][2048 + wwoff]     = m4;
        *(s16x4*)&Wbf[0][4096 + wwoff]     = l4;
        split3w4(wA1, h4, m4, l4);
        *(s16x4*)&Wbf[0][wwoff + 4]        = h4;
        *(s16x4*)&Wbf[0][2048 + wwoff + 4] = m4;
        *(s16x4*)&Wbf[0][4096 + wwoff + 4] = l4;
    }
    float4 wB0 = *(const float4*)(gWf + 32);  // W it=1
    float4 wB1 = *(const float4*)(gWf + 36);
    asm volatile("s_waitcnt vmcnt(2) lgkmcnt(0)" ::: "memory");
    __builtin_amdgcn_s_barrier();
    __builtin_amdgcn_sched_barrier(0);

    auto body = [&](int it, float4& ws0, float4& ws1, float4& wl0,
                    float4& wl1) {
        int nb = (it + 1) & 1;
        if (it < 63) {
#pragma unroll
            for (int q = 0; q < 4; q++)
                load_lds16(gA[q] + (it + 1) * 32,
                           &Asm[nb][q * 2048 + wv * 512]);
            __builtin_amdgcn_sched_barrier(0);
            s16x4 h4, m4, l4;
            split3w4(ws0, h4, m4, l4);
            *(s16x4*)&Wbf[nb][wwoff]            = h4;
            *(s16x4*)&Wbf[nb][2048 + wwoff]     = m4;
            *(s16x4*)&Wbf[nb][4096 + wwoff]     = l4;
            split3w4(ws1, h4, m4, l4);
            *(s16x4*)&Wbf[nb][wwoff + 4]        = h4;
            *(s16x4*)&Wbf[nb][2048 + wwoff + 4] = m4;
            *(s16x4*)&Wbf[nb][4096 + wwoff + 4] = l4;
        }
        if (it < 62) {
            wl0 = *(const float4*)(gWf + (it + 2) * 32);
            wl1 = *(const float4*)(gWf + (it + 2) * 32 + 4);
            __builtin_amdgcn_sched_barrier(0);
        }

        const short* as = Asm[it & 1];
        const short* wb = Wbf[it & 1];
        s16x8 av[8];
#pragma unroll
        for (int i = 0; i < 8; i++)
            av[i] = *(const s16x8*)(as + aoff[i]);
        s16x8 bfr[3][2];
#pragma unroll
        for (int oi = 0; oi < 2; oi++)
#pragma unroll
            for (int sp = 0; sp < 3; sp++)
                bfr[sp][oi] = *(const s16x8*)(wb + sp * 2048 + wroff[oi]);

#pragma unroll
        for (int i = 0; i < 8; i++)
#pragma unroll
            for (int oi = 0; oi < 2; oi++) {
                acc[i][oi] = __builtin_amdgcn_mfma_f32_16x16x32_bf16(
                    av[i], bfr[0][oi], acc[i][oi], 0, 0, 0);
                acc[i][oi] = __builtin_amdgcn_mfma_f32_16x16x32_bf16(
                    av[i], bfr[1][oi], acc[i][oi], 0, 0, 0);
                acc[i][oi] = __builtin_amdgcn_mfma_f32_16x16x32_bf16(
                    av[i], bfr[2][oi], acc[i][oi], 0, 0, 0);
            }

        if (it < 62) {
            asm volatile("s_waitcnt vmcnt(2) lgkmcnt(0)" ::: "memory");
            __builtin_amdgcn_s_barrier();
            __builtin_amdgcn_sched_barrier(0);
        } else if (it == 62) {
            asm volatile("s_waitcnt vmcnt(0) lgkmcnt(0)" ::: "memory");
            __builtin_amdgcn_s_barrier();
            __builtin_amdgcn_sched_barrier(0);
        }
    };

#pragma unroll 1
    for (int j = 0; j < 32; ++j) {
        body(2 * j,     wB0, wB1, wA0, wA1);
        body(2 * j + 1, wA0, wA1, wB0, wB1);
    }

    int col = lane & 15;
    int rq  = (lane >> 4) * 4;
#pragma unroll
    for (int i = 0; i < 8; i++)
#pragma unroll
        for (int oi = 0; oi < 2; oi++)
#pragma unroll
            for (int r = 0; r < 4; r++) {
                int m = mq * 128 + i * 16 + rq + r;
                int o = o0 + (2 * oh + oi) * 16 + col;
                part[((size_t)ks * 256 + m) * 4096 + o] = acc[i][oi][r];
            }
}

// ----------------------------------------------- K-split reduce + IF for fc1
__global__ void k_fc1_if(const float* __restrict__ part,
                         float* __restrict__ spk3) {
    int idx = blockIdx.x * 256 + threadIdx.x;   // 131072
    int o = idx & 4095;
    int n = idx >> 12;
    float v = 0.f;
    for (int t = 0; t < T_STEPS; t++) {
        int m = t * NB + n;
        float s = 0.f;
#pragma unroll
        for (int ks = 0; ks < 8; ks++)
            s += part[((size_t)ks * 256 + m) * 4096 + o];
        v += s;
        float sp = (v >= 1.f) ? 1.f : 0.f;
        if (sp > 0.f) v = 0.f;
        spk3[(size_t)m * 4096 + o] = sp;
    }
}

// ------------------------------------------------------ fc2 + IF + time-mean
__global__ __launch_bounds__(256) void k_fc2_if_mean(
        const float* __restrict__ spk3, const float* __restrict__ fc2,
        float* __restrict__ out) {
    int b = blockIdx.x;                  // 320 = 32n * 10o
    int n = b / 10, o = b % 10;
    const float* wr = fc2 + o * 4096;
    __shared__ float red[256];
    int tid = threadIdx.x;
    float v = 0.f, cnt = 0.f;
    for (int t = 0; t < T_STEPS; t++) {
        const float* row = spk3 + (size_t)(t * NB + n) * 4096;
        float p = 0.f;
        for (int i = tid; i < 4096; i += 256) p += row[i] * wr[i];
        red[tid] = p;
        __syncthreads();
        for (int s = 128; s > 0; s >>= 1) {
            if (tid < s) red[tid] += red[tid + s];
            __syncthreads();
        }
        if (tid == 0) {
            v += red[0];
            float sp = (v >= 1.f) ? 1.f : 0.f;
            cnt += sp;
            if (sp > 0.f) v = 0.f;
        }
        __syncthreads();
    }
    if (tid == 0) out[n * 10 + o] = cnt * 0.125f;
}

// ---------------------------------------------------------------------- launch
extern "C" void kernel_launch(void* const* d_in, const int* in_sizes, int n_in,
                              void* d_out, int out_size, void* d_ws, size_t ws_size,
                              hipStream_t stream) {
    const float* x   = (const float*)d_in[0];   // [8,32,3,64,64]
    const float* w1  = (const float*)d_in[1];   // [64,3,3,3]
    const float* w2  = (const float*)d_in[2];   // [64,64,3,3]
    const float* fc1 = (const float*)d_in[3];   // [4096,16384]
    const float* fc2 = (const float*)d_in[4];   // [10,4096]
    float* out = (float*)d_out;                 // [32,10]

    float* ws = (float*)d_ws;
    // workspace layout (float slots)
    const size_t off_w2s   = 0;                          // 57344 (110592 bf16)
    const size_t off_spk1p = 57344;                      // 8388608 (16.8M bf16)
    const size_t off_spk2  = off_spk1p + 8388608;        // 2097152 (4.2M bf16)
    const size_t off_part  = off_spk2 + 2097152;         // 8388608
    const size_t off_spk3  = off_part + 8388608;         // 1048576
    __bf16* w2s   = (__bf16*)(ws + off_w2s);
    __bf16* spk1p = (__bf16*)(ws + off_spk1p);
    __bf16* spk2  = (__bf16*)(ws + off_spk2);
    float*  part  = ws + off_part;
    float*  spk3  = ws + off_spk3;

    k_w2s<<<144, 256, 0, stream>>>(w2, w2s);
    k_conv1_if_pool<<<1024, 256, 0, stream>>>(x, w1, spk1p);
    k_conv2_if_pool<<<256, 512, 0, stream>>>((const short*)spk1p,
                                             (const short*)w2s, spk2);
    k_fc1_mfma<<<512, 256, 0, stream>>>((const short*)spk2, fc1, part);
    k_fc1_if<<<512, 256, 0, stream>>>(part, spk3);
    k_fc2_if_mean<<<320, 256, 0, stream>>>(spk3, fc2, out);
}

// Round 14
// 587.678 us; speedup vs baseline: 1.0990x; 1.0607x over previous
//
#include <hip/hip_runtime.h>
#include <hip/hip_bf16.h>

// SNN forward: conv1(3->64,3x3,p1) -> IF -> pool2 -> conv2(64->64) -> IF -> pool2
//              -> fc1(16384->4096) -> IF -> fc2(4096->10) -> IF -> mean over T
// T=8 N=32 IMG=64.
// conv2 and fc1 use bf16 MFMA: spikes are exactly 0/1 (exact in bf16); fp32
// weights are 3-way bf16 split (hi+mid+lo, residual <= 2^-25|w|) -> three MFMAs
// into one fp32 accumulator == fp32 dot product to within fp32 rounding noise.
// conv1 (R14): VALU-issue bound (R12: VALUBusy 53%, loads already hidden by
// R13's LDS staging which was +3us only). The 864 scalar v_fmac per thread
// per t are now 432 v_pk_fma_f32: accumulators (a0,a1) and (a2,a3) share the
// weight and use adjacent patch elements -> f32x2 pairs via
// __builtin_elementwise_fma. IEEE fma per lane, same per-accumulator chain
// order -> bit-identical output.
// fc1 (R12): 4-wave blocks, wave = 128 M-rows x 32 outs; cooperative W split3
// once per K-step -> pre-split bf16 LDS; A slab DMA double-buffer;
// counted-vmcnt barrier.
// conv2 (R5): A tile (zero-padded, 42.5 KB) DMA-staged per t; inner loop is
// pure ds_read_b128 + MFMA, no bounds checks; 16B-slot swizzle on DMA source.

#define T_STEPS 8
#define NB      32
#define CMID    64

typedef __bf16 bf16x2 __attribute__((ext_vector_type(2)));
typedef __bf16 bf16x4 __attribute__((ext_vector_type(4)));
typedef __bf16 bf16x8 __attribute__((ext_vector_type(8)));
typedef short  s16x4  __attribute__((ext_vector_type(4)));
typedef short  s16x8  __attribute__((ext_vector_type(8)));
typedef float  f32x2  __attribute__((ext_vector_type(2)));
typedef float  f32x4  __attribute__((ext_vector_type(4)));

struct Split3 { float h, m, l; };
__device__ __forceinline__ Split3 split3(float x) {
    Split3 s;
    __bf16 h = (__bf16)x;
    float r1 = x - (float)h;
    __bf16 m = (__bf16)r1;
    float r2 = r1 - (float)m;
    __bf16 l = (__bf16)r2;
    s.h = (float)h; s.m = (float)m; s.l = (float)l;
    return s;
}

// split 4 fp32 into three bf16x4 (hi/mid/lo), bit-identical to split3()
__device__ __forceinline__ void split3w4(float4 v, s16x4& fh, s16x4& fm,
                                         s16x4& fl) {
    float x[4] = {v.x, v.y, v.z, v.w};
    s16x4 h, m, l;
#pragma unroll
    for (int j = 0; j < 4; j++) {
        __bf16 ch = (__bf16)x[j];
        float r1 = x[j] - (float)ch;
        __bf16 cm = (__bf16)r1;
        float r2 = r1 - (float)cm;
        __bf16 cl = (__bf16)r2;
        h[j] = __builtin_bit_cast(short, ch);
        m[j] = __builtin_bit_cast(short, cm);
        l[j] = __builtin_bit_cast(short, cl);
    }
    fh = h; fm = m; fl = l;
}

// async global(16B/lane) -> LDS, wave-uniform dest base + lane*16
__device__ __forceinline__ void load_lds16(const void* g, void* l) {
    __builtin_amdgcn_global_load_lds(
        (const __attribute__((address_space(1))) void*)g,
        (__attribute__((address_space(3))) void*)l, 16, 0, 0);
}

// ------------------------------------------------- w2 -> 3-way-split frag order
__global__ void k_w2s(const float* __restrict__ w2, __bf16* __restrict__ w2s) {
    int idx = blockIdx.x * 256 + threadIdx.x;   // 36864 total
    int j    = idx & 7;
    int lane = (idx >> 3) & 63;
    int oh   = (idx >> 9) & 1;
    int kh   = (idx >> 10) & 1;
    int g    = idx >> 11;          // ch*9 + tap, 0..17
    int tap  = g % 9;
    int ch   = g / 9;
    int co = ch * 32 + oh * 16 + (lane & 15);
    int ci = kh * 32 + (lane >> 4) * 8 + j;
    float w = w2[co * 576 + ci * 9 + tap];
    Split3 s = split3(w);
    __bf16* o = w2s + (((size_t)(g * 2 + kh) * 2 + oh) * 3) * 512 + lane * 8 + j;
    o[0]    = (__bf16)s.h;
    o[512]  = (__bf16)s.m;
    o[1024] = (__bf16)s.l;
}

// ------------------------------------------ conv1 + IF + maxpool -> NHWC bf16
// x tile DMA-staged in LDS, double-buffered across t; FMA loop packed as
// v_pk_fma_f32 pairs (a0,a1)/(a2,a3). Values bit-identical to the scalar
// bounds-checked original.
__global__ __launch_bounds__(256) void k_conv1_if_pool(
        const float* __restrict__ x, const float* __restrict__ w1,
        __bf16* __restrict__ spk1p) {
    int b    = blockIdx.x;              // 1024 = 32n * 8cog * 4pht
    int n    = b >> 5;
    int cog  = (b >> 2) & 7;
    int pht  = b & 3;
    int tid  = threadIdx.x;
    int pw   = tid & 31;
    int phl  = tid >> 5;                // 0..7 (local pooled row)
    int wv   = tid >> 6;                // 0..3
    int lane = tid & 63;

    // tile row tr <-> global row gr = 16*pht - 1 + tr, tr in [0,17]
    __shared__ float Xt[2][3][18][64];  // 27.6 KB

    {   // zero both buffers once (covers never-DMA'd OOB rows for pht 0/3)
        float* xz = &Xt[0][0][0][0];
        for (int i = tid; i < 6912; i += 256) xz[i] = 0.f;
    }

    int trlo = (pht == 0) ? 1 : 0;      // valid tile rows [trlo, trhi]
    int trhi = (pht == 3) ? 16 : 17;

    // stage x[t] tile into Xt[buf]: 15 wave-uniform 4-row (1 KB) issues,
    // last issue per ci overlaps to cover the 17/18-row range exactly.
    auto stage = [&](int t, int buf) {
        const float* xb = x + (size_t)(t * NB + n) * 3 * 4096;
        for (int i = wv; i < 15; i += 4) {
            int ci  = i / 5, q = i % 5;
            int tr0 = (q < 4) ? (trlo + 4 * q) : (trhi - 3);
            int gr0 = 16 * pht - 1 + tr0;
            const float* src = xb + ci * 4096 + (gr0 + (lane >> 4)) * 64
                             + (lane & 15) * 4;
            load_lds16(src, &Xt[buf][ci][tr0][0]);
        }
    };

    __syncthreads();
    stage(0, 0);
    __syncthreads();

    bool pw0  = (pw == 0);
    bool pw31 = (pw == 31);
    int  cl   = pw0 ? 0 : (2 * pw - 1);   // clamped halo cols
    int  cr   = pw31 ? 63 : (2 * pw + 2);

    float v[8][4];
#pragma unroll
    for (int a = 0; a < 8; a++)
#pragma unroll
        for (int p = 0; p < 4; p++) v[a][p] = 0.f;

    for (int t = 0; t < T_STEPS; t++) {
        int buf = t & 1;
        if (t < T_STEPS - 1) stage(t + 1, buf ^ 1);

        float patch[3][4][4];
#pragma unroll
        for (int ci = 0; ci < 3; ci++)
#pragma unroll
            for (int dy = 0; dy < 4; dy++) {
                int tr = 2 * phl + dy;                  // 0..17
                const float* row = &Xt[buf][ci][tr][0];
                float2 mid = *(const float2*)(row + 2 * pw);
                float lv = row[cl];
                float rv = row[cr];
                patch[ci][dy][0] = pw0 ? 0.f : lv;
                patch[ci][dy][1] = mid.x;
                patch[ci][dy][2] = mid.y;
                patch[ci][dy][3] = pw31 ? 0.f : rv;
            }
        bf16x8 sv;
#pragma unroll
        for (int c8 = 0; c8 < 8; c8++) {
            int co = cog * 8 + c8;
            const float* wc = w1 + co * 27;   // wave-uniform -> s_load
            f32x2 a01 = {0.f, 0.f};           // (a0, a1): pool row ky
            f32x2 a23 = {0.f, 0.f};           // (a2, a3): pool row ky+1
#pragma unroll
            for (int ci = 0; ci < 3; ci++)
#pragma unroll
                for (int ky = 0; ky < 3; ky++)
#pragma unroll
                    for (int kx = 0; kx < 3; kx++) {
                        float w = wc[ci * 9 + ky * 3 + kx];
                        f32x2 wv2 = {w, w};
                        f32x2 p01 = {patch[ci][ky][kx],
                                     patch[ci][ky][kx + 1]};
                        f32x2 p23 = {patch[ci][ky + 1][kx],
                                     patch[ci][ky + 1][kx + 1]};
                        a01 = __builtin_elementwise_fma(wv2, p01, a01);
                        a23 = __builtin_elementwise_fma(wv2, p23, a23);
                    }
            float s0, s1, s2, s3;
            v[c8][0] += a01[0]; s0 = (v[c8][0] >= 1.f) ? 1.f : 0.f; if (s0 > 0.f) v[c8][0] = 0.f;
            v[c8][1] += a01[1]; s1 = (v[c8][1] >= 1.f) ? 1.f : 0.f; if (s1 > 0.f) v[c8][1] = 0.f;
            v[c8][2] += a23[0]; s2 = (v[c8][2] >= 1.f) ? 1.f : 0.f; if (s2 > 0.f) v[c8][2] = 0.f;
            v[c8][3] += a23[1]; s3 = (v[c8][3] >= 1.f) ? 1.f : 0.f; if (s3 > 0.f) v[c8][3] = 0.f;
            sv[c8] = (__bf16)fmaxf(fmaxf(s0, s1), fmaxf(s2, s3));
        }
        *(bf16x8*)(spk1p + ((size_t)(t * NB + n) * 1024
                            + (pht * 8 + phl) * 32 + pw) * 64 + cog * 8) = sv;

        __syncthreads();   // drains DMA (t+1 tile ready) + guards buf reuse
    }
}

// -------------------------------- conv2 (MFMA) + IF + maxpool fused, t in-kernel
__global__ __launch_bounds__(512, 2) void k_conv2_if_pool(
        const short* __restrict__ spk1p,   // [256][32][32][64] bf16 bits
        const short* __restrict__ w2s,     // [2][55296] bf16 bits (frag order)
        __bf16* __restrict__ spk2) {       // [256][64][16][16]
    int b     = blockIdx.x;                // 256 = 32n * 4s2 * 2ch
    int ch    = b & 1;
    int s2    = (b >> 1) & 3;
    int n     = b >> 3;
    int tid   = threadIdx.x;
    int lane  = tid & 63;
    int wv    = tid >> 6;                  // 0..7
    int mh    = wv >> 1, oh = wv & 1;      // mh 0..3
    int lm    = lane & 15, kq = lane >> 4;

    __shared__ short Bs[55296];            // 108 KB
    __shared__ short As[10 * 34 * 64];     // 42.5 KB

    {
        const uint4* src = (const uint4*)(w2s + (size_t)ch * 55296);
        uint4* dst = (uint4*)Bs;
        for (int i = tid; i < 6912; i += 512) dst[i] = src[i];
        uint4* za = (uint4*)As;
        for (int i = tid; i < 2720; i += 512) za[i] = (uint4){0, 0, 0, 0};
    }
    __syncthreads();
    const short* Bsw = Bs + oh * 1536;

    int wl  = lane >> 3;
    int sph = lane & 7;

    f32x4 v[4];
#pragma unroll
    for (int i = 0; i < 4; i++) v[i] = (f32x4){0.f, 0.f, 0.f, 0.f};

    int co = ch * 32 + oh * 16 + lm;
    int pH = s2 * 4 + mh;

#pragma unroll 1
    for (int t = 0; t < T_STEPS; t++) {
        const short* img = spk1p + (size_t)(t * NB + n) * 65536;

        if (t > 0) __syncthreads();
#pragma unroll
        for (int q = 0; q < 5; q++) {
            int u = q * 8 + wv;            // 0..39, wave-uniform
            int r = u >> 2;
            int quarter = u & 3;
            int hh = s2 * 8 - 1 + r;
            if ((unsigned)hh < 32u) {
                int widx = quarter * 8 + 1 + wl;
                int slog = sph ^ (widx & 7);
                const short* src = img + (size_t)(hh * 32 + widx - 1) * 64
                                       + slog * 8;
                short* dst = As + (r * 34 + quarter * 8 + 1) * 64;
                load_lds16(src, dst);
            }
        }
        __syncthreads();                   // drains DMA: As[t] ready

        f32x4 acc[4];
#pragma unroll
        for (int i = 0; i < 4; i++) acc[i] = (f32x4){0.f, 0.f, 0.f, 0.f};

#pragma unroll 1
        for (int dy = 0; dy < 3; dy++) {
#pragma unroll 1
            for (int dx = 0; dx < 3; dx++) {
                const short* bp = Bsw + (dy * 3 + dx) * 6144 + lane * 8;
                s16x8 bf[2][3];
#pragma unroll
                for (int kh = 0; kh < 2; kh++)
#pragma unroll
                    for (int sp = 0; sp < 3; sp++)
                        bf[kh][sp] = *(const s16x8*)(bp + kh * 3072 + sp * 512);
#pragma unroll
                for (int i = 0; i < 4; i++) {
                    int r    = 2 * mh + (i >> 1) + dy;              // 0..9
                    int widx = (i & 1) * 16 + lm + dx;              // 0..33
                    const short* ap = As + (r * 34 + widx) * 64;
                    s16x8 a0 = *(const s16x8*)(ap + ((kq    ) ^ (widx & 7)) * 8);
                    s16x8 a1 = *(const s16x8*)(ap + ((kq + 4) ^ (widx & 7)) * 8);
#pragma unroll
                    for (int sp = 0; sp < 3; sp++) {
                        acc[i] = __builtin_amdgcn_mfma_f32_16x16x32_bf16(
                            a0, bf[0][sp], acc[i], 0, 0, 0);
                        acc[i] = __builtin_amdgcn_mfma_f32_16x16x32_bf16(
                            a1, bf[1][sp], acc[i], 0, 0, 0);
                    }
                }
            }
        }
        float s[4][4];
#pragma unroll
        for (int i = 0; i < 4; i++)
#pragma unroll
            for (int r = 0; r < 4; r++) {
                float vv = v[i][r] + acc[i][r];
                float sp = (vv >= 1.f) ? 1.f : 0.f;
                s[i][r] = sp;
                v[i][r] = (sp > 0.f) ? 0.f : vv;
            }
        __bf16* op = spk2 + ((size_t)(t * NB + n) * 64 + co) * 256 + pH * 16
                   + kq * 2;
#pragma unroll
        for (int i2 = 0; i2 < 2; i2++) {
            float p0 = fmaxf(fmaxf(s[i2][0], s[i2][1]),
                             fmaxf(s[i2 + 2][0], s[i2 + 2][1]));
            float p1 = fmaxf(fmaxf(s[i2][2], s[i2][3]),
                             fmaxf(s[i2 + 2][2], s[i2 + 2][3]));
            bf16x2 pv = {(__bf16)p0, (__bf16)p1};
            *(bf16x2*)(op + i2 * 8) = pv;
        }
    }
}

// ----------------------------------------------------------- fc1 via bf16 MFMA
__global__ __launch_bounds__(256, 2) void k_fc1_mfma(
        const short* __restrict__ A,      // spk2 bf16 bits [256][16384]
        const float* __restrict__ W,      // fc1 [4096][16384]
        float* __restrict__ part) {       // [8][256][4096]
    int b  = blockIdx.x;                  // 512 = 64nt * 8ks
    int nt = b & 63;
    int ks = b >> 6;
    int o0 = nt * 64;
    int kbase = ks * 2048;

    int tid  = threadIdx.x;
    int lane = tid & 63;
    int wv   = tid >> 6;                  // 0..3
    int mq   = wv >> 1;                   // M half (128 rows)
    int oh   = wv & 1;                    // output half (32 of 64)
    int lm   = lane & 15;
    int kq   = lane >> 4;

    __shared__ short Asm[2][8192];        // 2 x 16 KB A slab (swizzled)
    __shared__ short Wbf[2][6144];        // 2 x 12 KB pre-split W bf16

    const short* gA[4];
#pragma unroll
    for (int q = 0; q < 4; q++) {
        int p = q * 256 + tid;
        int r = p >> 2;
        int c = (p & 3) ^ ((r >> 1) & 3);
        gA[q] = A + (size_t)r * 16384 + kbase + c * 8;
    }

    int wrow = tid >> 2;                  // 0..63
    const float* gWf = W + (size_t)(o0 + wrow) * 16384 + kbase + (tid & 3) * 8;

    int wkc   = tid & 3;
    int wwoff = wrow * 32 + (wkc ^ ((wrow >> 1) & 3)) * 8;

    int aoff[8];
#pragma unroll
    for (int i = 0; i < 8; i++) {
        int r = mq * 128 + i * 16 + lm;
        aoff[i] = (r * 4 + (kq ^ ((r >> 1) & 3))) * 8;
    }
    int wroff[2];
#pragma unroll
    for (int oi = 0; oi < 2; oi++) {
        int row = (2 * oh + oi) * 16 + lm;
        wroff[oi] = row * 32 + (kq ^ ((row >> 1) & 3)) * 8;
    }

    f32x4 acc[8][2];
#pragma unroll
    for (int i = 0; i < 8; i++)
#pragma unroll
        for (int oi = 0; oi < 2; oi++) acc[i][oi] = (f32x4){0.f, 0.f, 0.f, 0.f};

    float4 wA0 = *(const float4*)gWf;         // W it=0
    float4 wA1 = *(const float4*)(gWf + 4);
#pragma unroll
    for (int q = 0; q < 4; q++)
        load_lds16(gA[q], &Asm[0][q * 2048 + wv * 512]);
    {
        s16x4 h4, m4, l4;
        split3w4(wA0, h4, m4, l4);
        *(s16x4*)&Wbf[0][wwoff]            = h4;
        *(s16x4*)&Wbf[0][2048 + wwoff]     = m4;
        *(s16x4*)&Wbf[0][4096 + wwoff]     = l4;
        split3w4(wA1, h4, m4, l4);
        *(s16x4*)&Wbf[0][wwoff + 4]        = h4;
        *(s16x4*)&Wbf[0][2048 + wwoff + 4] = m4;
        *(s16x4*)&Wbf[0][4096 + wwoff + 4] = l4;
    }
    float4 wB0 = *(const float4*)(gWf + 32);  // W it=1
    float4 wB1 = *(const float4*)(gWf + 36);
    asm volatile("s_waitcnt vmcnt(2) lgkmcnt(0)" ::: "memory");
    __builtin_amdgcn_s_barrier();
    __builtin_amdgcn_sched_barrier(0);

    auto body = [&](int it, float4& ws0, float4& ws1, float4& wl0,
                    float4& wl1) {
        int nb = (it + 1) & 1;
        if (it < 63) {
#pragma unroll
            for (int q = 0; q < 4; q++)
                load_lds16(gA[q] + (it + 1) * 32,
                           &Asm[nb][q * 2048 + wv * 512]);
            __builtin_amdgcn_sched_barrier(0);
            s16x4 h4, m4, l4;
            split3w4(ws0, h4, m4, l4);
            *(s16x4*)&Wbf[nb][wwoff]            = h4;
            *(s16x4*)&Wbf[nb][2048 + wwoff]     = m4;
            *(s16x4*)&Wbf[nb][4096 + wwoff]     = l4;
            split3w4(ws1, h4, m4, l4);
            *(s16x4*)&Wbf[nb][wwoff + 4]        = h4;
            *(s16x4*)&Wbf[nb][2048 + wwoff + 4] = m4;
            *(s16x4*)&Wbf[nb][4096 + wwoff + 4] = l4;
        }
        if (it < 62) {
            wl0 = *(const float4*)(gWf + (it + 2) * 32);
            wl1 = *(const float4*)(gWf + (it + 2) * 32 + 4);
            __builtin_amdgcn_sched_barrier(0);
        }

        const short* as = Asm[it & 1];
        const short* wb = Wbf[it & 1];
        s16x8 av[8];
#pragma unroll
        for (int i = 0; i < 8; i++)
            av[i] = *(const s16x8*)(as + aoff[i]);
        s16x8 bfr[3][2];
#pragma unroll
        for (int oi = 0; oi < 2; oi++)
#pragma unroll
            for (int sp = 0; sp < 3; sp++)
                bfr[sp][oi] = *(const s16x8*)(wb + sp * 2048 + wroff[oi]);

#pragma unroll
        for (int i = 0; i < 8; i++)
#pragma unroll
            for (int oi = 0; oi < 2; oi++) {
                acc[i][oi] = __builtin_amdgcn_mfma_f32_16x16x32_bf16(
                    av[i], bfr[0][oi], acc[i][oi], 0, 0, 0);
                acc[i][oi] = __builtin_amdgcn_mfma_f32_16x16x32_bf16(
                    av[i], bfr[1][oi], acc[i][oi], 0, 0, 0);
                acc[i][oi] = __builtin_amdgcn_mfma_f32_16x16x32_bf16(
                    av[i], bfr[2][oi], acc[i][oi], 0, 0, 0);
            }

        if (it < 62) {
            asm volatile("s_waitcnt vmcnt(2) lgkmcnt(0)" ::: "memory");
            __builtin_amdgcn_s_barrier();
            __builtin_amdgcn_sched_barrier(0);
        } else if (it == 62) {
            asm volatile("s_waitcnt vmcnt(0) lgkmcnt(0)" ::: "memory");
            __builtin_amdgcn_s_barrier();
            __builtin_amdgcn_sched_barrier(0);
        }
    };

#pragma unroll 1
    for (int j = 0; j < 32; ++j) {
        body(2 * j,     wB0, wB1, wA0, wA1);
        body(2 * j + 1, wA0, wA1, wB0, wB1);
    }

    int col = lane & 15;
    int rq  = (lane >> 4) * 4;
#pragma unroll
    for (int i = 0; i < 8; i++)
#pragma unroll
        for (int oi = 0; oi < 2; oi++)
#pragma unroll
            for (int r = 0; r < 4; r++) {
                int m = mq * 128 + i * 16 + rq + r;
                int o = o0 + (2 * oh + oi) * 16 + col;
                part[((size_t)ks * 256 + m) * 4096 + o] = acc[i][oi][r];
            }
}

// ----------------------------------------------- K-split reduce + IF for fc1
__global__ void k_fc1_if(const float* __restrict__ part,
                         float* __restrict__ spk3) {
    int idx = blockIdx.x * 256 + threadIdx.x;   // 131072
    int o = idx & 4095;
    int n = idx >> 12;
    float v = 0.f;
    for (int t = 0; t < T_STEPS; t++) {
        int m = t * NB + n;
        float s = 0.f;
#pragma unroll
        for (int ks = 0; ks < 8; ks++)
            s += part[((size_t)ks * 256 + m) * 4096 + o];
        v += s;
        float sp = (v >= 1.f) ? 1.f : 0.f;
        if (sp > 0.f) v = 0.f;
        spk3[(size_t)m * 4096 + o] = sp;
    }
}

// ------------------------------------------------------ fc2 + IF + time-mean
__global__ __launch_bounds__(256) void k_fc2_if_mean(
        const float* __restrict__ spk3, const float* __restrict__ fc2,
        float* __restrict__ out) {
    int b = blockIdx.x;                  // 320 = 32n * 10o
    int n = b / 10, o = b % 10;
    const float* wr = fc2 + o * 4096;
    __shared__ float red[256];
    int tid = threadIdx.x;
    float v = 0.f, cnt = 0.f;
    for (int t = 0; t < T_STEPS; t++) {
        const float* row = spk3 + (size_t)(t * NB + n) * 4096;
        float p = 0.f;
        for (int i = tid; i < 4096; i += 256) p += row[i] * wr[i];
        red[tid] = p;
        __syncthreads();
        for (int s = 128; s > 0; s >>= 1) {
            if (tid < s) red[tid] += red[tid + s];
            __syncthreads();
        }
        if (tid == 0) {
            v += red[0];
            float sp = (v >= 1.f) ? 1.f : 0.f;
            cnt += sp;
            if (sp > 0.f) v = 0.f;
        }
        __syncthreads();
    }
    if (tid == 0) out[n * 10 + o] = cnt * 0.125f;
}

// ---------------------------------------------------------------------- launch
extern "C" void kernel_launch(void* const* d_in, const int* in_sizes, int n_in,
                              void* d_out, int out_size, void* d_ws, size_t ws_size,
                              hipStream_t stream) {
    const float* x   = (const float*)d_in[0];   // [8,32,3,64,64]
    const float* w1  = (const float*)d_in[1];   // [64,3,3,3]
    const float* w2  = (const float*)d_in[2];   // [64,64,3,3]
    const float* fc1 = (const float*)d_in[3];   // [4096,16384]
    const float* fc2 = (const float*)d_in[4];   // [10,4096]
    float* out = (float*)d_out;                 // [32,10]

    float* ws = (float*)d_ws;
    // workspace layout (float slots)
    const size_t off_w2s   = 0;                          // 57344 (110592 bf16)
    const size_t off_spk1p = 57344;                      // 8388608 (16.8M bf16)
    const size_t off_spk2  = off_spk1p + 8388608;        // 2097152 (4.2M bf16)
    const size_t off_part  = off_spk2 + 2097152;         // 8388608
    const size_t off_spk3  = off_part + 8388608;         // 1048576
    __bf16* w2s   = (__bf16*)(ws + off_w2s);
    __bf16* spk1p = (__bf16*)(ws + off_spk1p);
    __bf16* spk2  = (__bf16*)(ws + off_spk2);
    float*  part  = ws + off_part;
    float*  spk3  = ws + off_spk3;

    k_w2s<<<144, 256, 0, stream>>>(w2, w2s);
    k_conv1_if_pool<<<1024, 256, 0, stream>>>(x, w1, spk1p);
    k_conv2_if_pool<<<256, 512, 0, stream>>>((const short*)spk1p,
                                             (const short*)w2s, spk2);
    k_fc1_mfma<<<512, 256, 0, stream>>>((const short*)spk2, fc1, part);
    k_fc1_if<<<512, 256, 0, stream>>>(part, spk3);
    k_fc2_if_mean<<<320, 256, 0, stream>>>(spk3, fc2, out);
}